// Round 1
// baseline (1760.228 us; speedup 1.0000x reference)
//
#include <hip/hip_runtime.h>
#include <math.h>

#define SEQ    512
#define EMB    1024
#define NHEAD  16
#define DHEAD  64
#define NBAT   4
#define QSCALE 0.125f   // 1/sqrt(64)

// ---------------------------------------------------------------------------
// Interval linear:  out_v = Av@W + b
//                   out_l = Ac@W - Ar@|W| + b,  out_u = Ac@W + Ar@|W| + b
// where Ac=(Al+Au)/2, Ar=(Au-Al)/2 (computed during A-tile load).
// Tiles: BM=BN=64, BK=16, 256 threads, 4x4 per-thread micro-tile, 3 accums.
// ---------------------------------------------------------------------------
__global__ __launch_bounds__(256)
void ibp_linear_kernel(const float* __restrict__ Av,
                       const float* __restrict__ Al,
                       const float* __restrict__ Au,
                       const float* __restrict__ W,
                       const float* __restrict__ bias,
                       float* __restrict__ Ov,
                       float* __restrict__ Ol,
                       float* __restrict__ Ou,
                       int N, int K)
{
  __shared__ __attribute__((aligned(16))) float As_v[16][68];
  __shared__ __attribute__((aligned(16))) float As_c[16][68];
  __shared__ __attribute__((aligned(16))) float As_r[16][68];
  __shared__ __attribute__((aligned(16))) float Bs[16][68];

  const int t  = threadIdx.x;
  const int m0 = blockIdx.y * 64;
  const int n0 = blockIdx.x * 64;
  const int tm = (t >> 4) * 4;
  const int tn = (t & 15) * 4;
  const int la_m = t >> 2;         // 0..63
  const int la_k = (t & 3) * 4;    // 0,4,8,12
  const int lb_k = t >> 4;         // 0..15
  const int lb_n = (t & 15) * 4;   // 0..60

  float accv[4][4] = {}; float accc[4][4] = {}; float accr[4][4] = {};

  for (int k0 = 0; k0 < K; k0 += 16) {
    const int ga = (m0 + la_m) * K + k0 + la_k;
    float4 v4 = *(const float4*)(Av + ga);
    float4 l4 = *(const float4*)(Al + ga);
    float4 u4 = *(const float4*)(Au + ga);
    float4 w4 = *(const float4*)(W + (k0 + lb_k) * N + n0 + lb_n);
    float vv[4] = {v4.x, v4.y, v4.z, v4.w};
    float ll[4] = {l4.x, l4.y, l4.z, l4.w};
    float uu[4] = {u4.x, u4.y, u4.z, u4.w};
#pragma unroll
    for (int e = 0; e < 4; e++) {
      As_v[la_k + e][la_m] = vv[e];
      As_c[la_k + e][la_m] = 0.5f * (ll[e] + uu[e]);
      As_r[la_k + e][la_m] = 0.5f * (uu[e] - ll[e]);
    }
    *(float4*)&Bs[lb_k][lb_n] = w4;
    __syncthreads();
#pragma unroll
    for (int kk = 0; kk < 16; kk++) {
      float4 a4v = *(const float4*)&As_v[kk][tm];
      float4 a4c = *(const float4*)&As_c[kk][tm];
      float4 a4r = *(const float4*)&As_r[kk][tm];
      float4 b4  = *(const float4*)&Bs[kk][tn];
      float amv[4] = {a4v.x, a4v.y, a4v.z, a4v.w};
      float amc[4] = {a4c.x, a4c.y, a4c.z, a4c.w};
      float amr[4] = {a4r.x, a4r.y, a4r.z, a4r.w};
      float bv[4]  = {b4.x, b4.y, b4.z, b4.w};
      float ba[4]  = {fabsf(b4.x), fabsf(b4.y), fabsf(b4.z), fabsf(b4.w)};
#pragma unroll
      for (int i = 0; i < 4; i++)
#pragma unroll
        for (int j = 0; j < 4; j++) {
          accv[i][j] = fmaf(amv[i], bv[j], accv[i][j]);
          accc[i][j] = fmaf(amc[i], bv[j], accc[i][j]);
          accr[i][j] = fmaf(amr[i], ba[j], accr[i][j]);
        }
    }
    __syncthreads();
  }

  float4 b4 = *(const float4*)(bias + n0 + tn);
  float bb[4] = {b4.x, b4.y, b4.z, b4.w};
#pragma unroll
  for (int i = 0; i < 4; i++) {
    const int m = m0 + tm + i;
    float tv[4], tl[4], tu[4];
#pragma unroll
    for (int j = 0; j < 4; j++) {
      tv[j] = accv[i][j] + bb[j];
      tl[j] = accc[i][j] - accr[i][j] + bb[j];
      tu[j] = accc[i][j] + accr[i][j] + bb[j];
    }
    *(float4*)(Ov + m * N + n0 + tn) = *(const float4*)tv;
    *(float4*)(Ol + m * N + n0 + tn) = *(const float4*)tl;
    *(float4*)(Ou + m * N + n0 + tn) = *(const float4*)tu;
  }
}

// ---------------------------------------------------------------------------
// Fused IBP attention: one block per (b, h, q-row). Score row (val/lb/ub) in
// LDS; K/V read from global (L2-resident per (b,h)); softmax bounds; P@V.
// ---------------------------------------------------------------------------
__global__ __launch_bounds__(256)
void ibp_attn_kernel(const float* __restrict__ qkv_v,
                     const float* __restrict__ qkv_l,
                     const float* __restrict__ qkv_u,
                     float* __restrict__ o_v,
                     float* __restrict__ o_l,
                     float* __restrict__ o_u)
{
  const int s_q = blockIdx.x;
  const int h   = blockIdx.y;
  const int b   = blockIdx.z;
  const int t   = threadIdx.x;

  __shared__ __attribute__((aligned(16))) float q_vs[64];
  __shared__ __attribute__((aligned(16))) float q_lp[64];
  __shared__ __attribute__((aligned(16))) float q_ln[64];
  __shared__ __attribute__((aligned(16))) float q_up[64];
  __shared__ __attribute__((aligned(16))) float q_un[64];
  __shared__ float s_v[512], s_l[512], s_u[512];
  __shared__ float red[20];
  __shared__ float o_part[4][3][64];

  const int mq = b * SEQ + s_q;

  // ---- load + pre-clamp scaled q row ----
  if (t < 64) {
    const int qi = mq * 3072 + h * 64 + t;
    float qv = qkv_v[qi] * QSCALE;
    float ql = qkv_l[qi] * QSCALE;
    float qu = qkv_u[qi] * QSCALE;
    q_vs[t] = qv;
    q_lp[t] = fmaxf(ql, 0.f); q_ln[t] = fminf(ql, 0.f);
    q_up[t] = fmaxf(qu, 0.f); q_un[t] = fminf(qu, 0.f);
  }
  __syncthreads();

  // ---- scores: 8 lanes per column (d-split), shfl-reduce ----
  const int cgrp = t >> 3;   // 0..31
  const int dgrp = t & 7;    // 0..7
  for (int it = 0; it < 16; it++) {
    const int c  = it * 32 + cgrp;
    const int rk = (b * SEQ + c) * 3072 + 1024 + h * 64;
    float sv = 0.f, sl = 0.f, su = 0.f;
#pragma unroll
    for (int half = 0; half < 2; half++) {
      const int d = half * 32 + dgrp * 4;
      float4 kvf = *(const float4*)(qkv_v + rk + d);
      float4 klf = *(const float4*)(qkv_l + rk + d);
      float4 kuf = *(const float4*)(qkv_u + rk + d);
      float4 qvf  = *(const float4*)(q_vs + d);
      float4 qlpf = *(const float4*)(q_lp + d);
      float4 qlnf = *(const float4*)(q_ln + d);
      float4 qupf = *(const float4*)(q_up + d);
      float4 qunf = *(const float4*)(q_un + d);
      float kv[4]  = {kvf.x, kvf.y, kvf.z, kvf.w};
      float kl[4]  = {klf.x, klf.y, klf.z, klf.w};
      float ku[4]  = {kuf.x, kuf.y, kuf.z, kuf.w};
      float qv[4]  = {qvf.x, qvf.y, qvf.z, qvf.w};
      float qlp[4] = {qlpf.x, qlpf.y, qlpf.z, qlpf.w};
      float qln[4] = {qlnf.x, qlnf.y, qlnf.z, qlnf.w};
      float qup[4] = {qupf.x, qupf.y, qupf.z, qupf.w};
      float qun[4] = {qunf.x, qunf.y, qunf.z, qunf.w};
#pragma unroll
      for (int e = 0; e < 4; e++) {
        sv = fmaf(qv[e], kv[e], sv);
        float klp = fmaxf(kl[e], 0.f), kln = fminf(kl[e], 0.f);
        float kup = fmaxf(ku[e], 0.f), kun = fminf(ku[e], 0.f);
        sl = fmaf(qlp[e], klp, sl); sl = fmaf(qup[e], kln, sl);
        sl = fmaf(qln[e], kup, sl); sl = fmaf(qun[e], kun, sl);
        su = fmaf(qup[e], kup, su); su = fmaf(qlp[e], kun, su);
        su = fmaf(qun[e], klp, su); su = fmaf(qln[e], kln, su);
      }
    }
#pragma unroll
    for (int m = 1; m <= 4; m <<= 1) {
      sv += __shfl_xor(sv, m, 64);
      sl += __shfl_xor(sl, m, 64);
      su += __shfl_xor(su, m, 64);
    }
    if (dgrp == 0) { s_v[c] = sv; s_l[c] = sl; s_u[c] = su; }
  }
  __syncthreads();

  // ---- softmax bounds over the 512-row ----
  const int lane = t & 63;
  const int wid  = t >> 6;
  float mv = fmaxf(s_v[t], s_v[t + 256]);
  float mu = fmaxf(s_u[t], s_u[t + 256]);
#pragma unroll
  for (int m = 1; m < 64; m <<= 1) {
    mv = fmaxf(mv, __shfl_xor(mv, m, 64));
    mu = fmaxf(mu, __shfl_xor(mu, m, 64));
  }
  if (lane == 0) { red[wid] = mv; red[4 + wid] = mu; }
  __syncthreads();
  mv = fmaxf(fmaxf(red[0], red[1]), fmaxf(red[2], red[3]));
  mu = fmaxf(fmaxf(red[4], red[5]), fmaxf(red[6], red[7]));

  float psv = 0.f, psl = 0.f, psu = 0.f;
#pragma unroll
  for (int i = 0; i < 2; i++) {
    const int c = t + i * 256;
    float ev = __expf(s_v[c] - mv);
    float el = __expf(s_l[c] - mu);
    float eu = __expf(s_u[c] - mu);
    s_v[c] = ev; s_l[c] = el; s_u[c] = eu;
    psv += ev; psl += el; psu += eu;
  }
#pragma unroll
  for (int m = 1; m < 64; m <<= 1) {
    psv += __shfl_xor(psv, m, 64);
    psl += __shfl_xor(psl, m, 64);
    psu += __shfl_xor(psu, m, 64);
  }
  if (lane == 0) { red[8 + wid] = psv; red[12 + wid] = psl; red[16 + wid] = psu; }
  __syncthreads();
  const float Svs = red[8]  + red[9]  + red[10] + red[11];
  const float Slo = red[12] + red[13] + red[14] + red[15];
  const float Sup = red[16] + red[17] + red[18] + red[19];
#pragma unroll
  for (int i = 0; i < 2; i++) {
    const int c = t + i * 256;
    float ev = s_v[c], el = s_l[c], eu = s_u[c];
    float pv = ev / Svs;
    float pl = el / (Sup - eu + el);
    float pu = eu / (Slo - el + eu);
    s_v[c] = pv;
    s_l[c] = fminf(fmaxf(pl, 0.f), 1.f);
    s_u[c] = fminf(fmaxf(pu, 0.f), 1.f);
  }
  __syncthreads();

  // ---- P @ V (pl,pu >= 0 after clip, so only pos/neg of V needed) ----
  const int d   = t & 63;
  const int grp = t >> 6;
  float ov = 0.f, ol = 0.f, ou = 0.f;
  const int vcol = 2048 + h * 64 + d;
#pragma unroll 4
  for (int j = 0; j < 128; j++) {
    const int c  = grp * 128 + j;
    const float pv = s_v[c], pl = s_l[c], pu = s_u[c];
    const int rv = (b * SEQ + c) * 3072 + vcol;
    const float vvv = qkv_v[rv], vl = qkv_l[rv], vu = qkv_u[rv];
    ov = fmaf(pv, vvv, ov);
    ol = fmaf(pl, fmaxf(vl, 0.f), ol); ol = fmaf(pu, fminf(vl, 0.f), ol);
    ou = fmaf(pu, fmaxf(vu, 0.f), ou); ou = fmaf(pl, fminf(vu, 0.f), ou);
  }
  o_part[grp][0][d] = ov;
  o_part[grp][1][d] = ol;
  o_part[grp][2][d] = ou;
  __syncthreads();
  if (t < 64) {
    const int ro = mq * 1024 + h * 64 + t;
    o_v[ro] = o_part[0][0][t] + o_part[1][0][t] + o_part[2][0][t] + o_part[3][0][t];
    o_l[ro] = o_part[0][1][t] + o_part[1][1][t] + o_part[2][1][t] + o_part[3][1][t];
    o_u[ro] = o_part[0][2][t] + o_part[1][2][t] + o_part[2][2][t] + o_part[3][2][t];
  }
}

// ---------------------------------------------------------------------------
extern "C" void kernel_launch(void* const* d_in, const int* in_sizes, int n_in,
                              void* d_out, int out_size, void* d_ws, size_t ws_size,
                              hipStream_t stream)
{
  const float* x_val = (const float*)d_in[0];
  const float* x_lb  = (const float*)d_in[1];
  const float* x_ub  = (const float*)d_in[2];
  const float* Wi    = (const float*)d_in[3];
  const float* bi    = (const float*)d_in[4];
  const float* Wo    = (const float*)d_in[5];
  const float* bo    = (const float*)d_in[6];
  float* out = (float*)d_out;

  // workspace layout (fp32): qkv v/l/u [2048][3072], o v/l/u [2048][1024] = 96 MB
  float* ws    = (float*)d_ws;
  float* qkv_v = ws;
  float* qkv_l = qkv_v + (size_t)2048 * 3072;
  float* qkv_u = qkv_l + (size_t)2048 * 3072;
  float* ov    = qkv_u + (size_t)2048 * 3072;
  float* ol    = ov + (size_t)2048 * 1024;
  float* ou    = ol + (size_t)2048 * 1024;

  // 1) in_proj interval linear: [2048,1024] @ [1024,3072]
  ibp_linear_kernel<<<dim3(3072 / 64, 2048 / 64), 256, 0, stream>>>(
      x_val, x_lb, x_ub, Wi, bi, qkv_v, qkv_l, qkv_u, 3072, 1024);

  // 2) fused IBP attention per (b,h,row)
  ibp_attn_kernel<<<dim3(SEQ, NHEAD, NBAT), 256, 0, stream>>>(
      qkv_v, qkv_l, qkv_u, ov, ol, ou);

  // 3) out_proj interval linear: [2048,1024] @ [1024,1024] -> stacked [3,B,S,E]
  ibp_linear_kernel<<<dim3(1024 / 64, 2048 / 64), 256, 0, stream>>>(
      ov, ol, ou, Wo, bo,
      out, out + (size_t)2048 * 1024, out + (size_t)4096 * 1024, 1024, 1024);
}

// Round 2
// 1398.521 us; speedup vs baseline: 1.2586x; 1.2586x over previous
//
#include <hip/hip_runtime.h>
#include <math.h>

#define SEQ    512
#define EMB    1024
#define NHEAD  16
#define DHEAD  64
#define NBAT   4
#define QSCALE 0.125f   // 1/sqrt(64)
#define QT     8        // q-rows per attention block

// ---------------------------------------------------------------------------
// Interval linear:  out_v = Av@W + b
//                   out_l = Ac@W - Ar@|W| + b,  out_u = Ac@W + Ar@|W| + b
// ---------------------------------------------------------------------------
__global__ __launch_bounds__(256)
void ibp_linear_kernel(const float* __restrict__ Av,
                       const float* __restrict__ Al,
                       const float* __restrict__ Au,
                       const float* __restrict__ W,
                       const float* __restrict__ bias,
                       float* __restrict__ Ov,
                       float* __restrict__ Ol,
                       float* __restrict__ Ou,
                       int N, int K)
{
  __shared__ __attribute__((aligned(16))) float As_v[16][68];
  __shared__ __attribute__((aligned(16))) float As_c[16][68];
  __shared__ __attribute__((aligned(16))) float As_r[16][68];
  __shared__ __attribute__((aligned(16))) float Bs[16][68];

  const int t  = threadIdx.x;
  const int m0 = blockIdx.y * 64;
  const int n0 = blockIdx.x * 64;
  const int tm = (t >> 4) * 4;
  const int tn = (t & 15) * 4;
  const int la_m = t >> 2;
  const int la_k = (t & 3) * 4;
  const int lb_k = t >> 4;
  const int lb_n = (t & 15) * 4;

  float accv[4][4] = {}; float accc[4][4] = {}; float accr[4][4] = {};

  for (int k0 = 0; k0 < K; k0 += 16) {
    const int ga = (m0 + la_m) * K + k0 + la_k;
    float4 v4 = *(const float4*)(Av + ga);
    float4 l4 = *(const float4*)(Al + ga);
    float4 u4 = *(const float4*)(Au + ga);
    float4 w4 = *(const float4*)(W + (k0 + lb_k) * N + n0 + lb_n);
    float vv[4] = {v4.x, v4.y, v4.z, v4.w};
    float ll[4] = {l4.x, l4.y, l4.z, l4.w};
    float uu[4] = {u4.x, u4.y, u4.z, u4.w};
#pragma unroll
    for (int e = 0; e < 4; e++) {
      As_v[la_k + e][la_m] = vv[e];
      As_c[la_k + e][la_m] = 0.5f * (ll[e] + uu[e]);
      As_r[la_k + e][la_m] = 0.5f * (uu[e] - ll[e]);
    }
    *(float4*)&Bs[lb_k][lb_n] = w4;
    __syncthreads();
#pragma unroll
    for (int kk = 0; kk < 16; kk++) {
      float4 a4v = *(const float4*)&As_v[kk][tm];
      float4 a4c = *(const float4*)&As_c[kk][tm];
      float4 a4r = *(const float4*)&As_r[kk][tm];
      float4 b4  = *(const float4*)&Bs[kk][tn];
      float amv[4] = {a4v.x, a4v.y, a4v.z, a4v.w};
      float amc[4] = {a4c.x, a4c.y, a4c.z, a4c.w};
      float amr[4] = {a4r.x, a4r.y, a4r.z, a4r.w};
      float bv[4]  = {b4.x, b4.y, b4.z, b4.w};
      float ba[4]  = {fabsf(b4.x), fabsf(b4.y), fabsf(b4.z), fabsf(b4.w)};
#pragma unroll
      for (int i = 0; i < 4; i++)
#pragma unroll
        for (int j = 0; j < 4; j++) {
          accv[i][j] = fmaf(amv[i], bv[j], accv[i][j]);
          accc[i][j] = fmaf(amc[i], bv[j], accc[i][j]);
          accr[i][j] = fmaf(amr[i], ba[j], accr[i][j]);
        }
    }
    __syncthreads();
  }

  float4 b4 = *(const float4*)(bias + n0 + tn);
  float bb[4] = {b4.x, b4.y, b4.z, b4.w};
#pragma unroll
  for (int i = 0; i < 4; i++) {
    const int m = m0 + tm + i;
    float tv[4], tl[4], tu[4];
#pragma unroll
    for (int j = 0; j < 4; j++) {
      tv[j] = accv[i][j] + bb[j];
      tl[j] = accc[i][j] - accr[i][j] + bb[j];
      tu[j] = accc[i][j] + accr[i][j] + bb[j];
    }
    *(float4*)(Ov + m * N + n0 + tn) = *(const float4*)tv;
    *(float4*)(Ol + m * N + n0 + tn) = *(const float4*)tl;
    *(float4*)(Ou + m * N + n0 + tn) = *(const float4*)tu;
  }
}

// ---------------------------------------------------------------------------
// Fused IBP attention, QT q-rows per block. K/V loaded once per block and
// reused (registers) across all QT rows; scores in LDS; softmax bounds; P@V.
// ---------------------------------------------------------------------------
__global__ __launch_bounds__(256)
void ibp_attn_kernel(const float* __restrict__ qkv_v,
                     const float* __restrict__ qkv_l,
                     const float* __restrict__ qkv_u,
                     float* __restrict__ o_v,
                     float* __restrict__ o_l,
                     float* __restrict__ o_u)
{
  const int qblk = blockIdx.x;          // 0..SEQ/QT-1
  const int h    = blockIdx.y;
  const int b    = blockIdx.z;
  const int t    = threadIdx.x;
  const int q0   = qblk * QT;

  // LDS: scores [3][QT][512] = 48 KB, q-block [5][QT][64] = 10 KB
  __shared__ __attribute__((aligned(16))) float smem[12288 + 2560];
  float* s_v = smem;            // [QT][512]
  float* s_l = smem + 4096;
  float* s_u = smem + 8192;
  float* qb  = smem + 12288;    // [5][QT*64]: qv, qlp, qln, qup, qun

  // ---- load + pre-clamp scaled q block ----
  for (int i = t; i < QT * 64; i += 256) {
    const int q = i >> 6, d = i & 63;
    const int gi = (b * SEQ + q0 + q) * 3072 + h * 64 + d;
    const float qv = qkv_v[gi] * QSCALE;
    const float ql = qkv_l[gi] * QSCALE;
    const float qu = qkv_u[gi] * QSCALE;
    qb[0 * 512 + i] = qv;
    qb[1 * 512 + i] = fmaxf(ql, 0.f);
    qb[2 * 512 + i] = fminf(ql, 0.f);
    qb[3 * 512 + i] = fmaxf(qu, 0.f);
    qb[4 * 512 + i] = fminf(qu, 0.f);
  }
  __syncthreads();

  // ---- scores: 32 columns in flight, 8 lanes per column (8 d each) ----
  const int cgrp = t >> 3;   // 0..31
  const int dgrp = t & 7;    // 0..7
  for (int it = 0; it < 16; it++) {
    const int c  = it * 32 + cgrp;
    const int rk = (b * SEQ + c) * 3072 + 1024 + h * 64;
    // load + clamp this thread's 8 K elements ONCE, reuse across QT rows
    float kv[8], klp[8], kln[8], kup[8], kun[8];
#pragma unroll
    for (int half = 0; half < 2; half++) {
      const int d = half * 32 + dgrp * 4;
      float4 kvf = *(const float4*)(qkv_v + rk + d);
      float4 klf = *(const float4*)(qkv_l + rk + d);
      float4 kuf = *(const float4*)(qkv_u + rk + d);
      float kvt[4] = {kvf.x, kvf.y, kvf.z, kvf.w};
      float klt[4] = {klf.x, klf.y, klf.z, klf.w};
      float kut[4] = {kuf.x, kuf.y, kuf.z, kuf.w};
#pragma unroll
      for (int e = 0; e < 4; e++) {
        const int idx = half * 4 + e;
        kv[idx]  = kvt[e];
        klp[idx] = fmaxf(klt[e], 0.f); kln[idx] = fminf(klt[e], 0.f);
        kup[idx] = fmaxf(kut[e], 0.f); kun[idx] = fminf(kut[e], 0.f);
      }
    }
#pragma unroll
    for (int q = 0; q < QT; q++) {
      float sv = 0.f, sl = 0.f, su = 0.f;
#pragma unroll
      for (int half = 0; half < 2; half++) {
        const int d = half * 32 + dgrp * 4;
        float4 qvf  = *(const float4*)&qb[0 * 512 + q * 64 + d];
        float4 qlpf = *(const float4*)&qb[1 * 512 + q * 64 + d];
        float4 qlnf = *(const float4*)&qb[2 * 512 + q * 64 + d];
        float4 qupf = *(const float4*)&qb[3 * 512 + q * 64 + d];
        float4 qunf = *(const float4*)&qb[4 * 512 + q * 64 + d];
        float qv[4]  = {qvf.x, qvf.y, qvf.z, qvf.w};
        float qlp[4] = {qlpf.x, qlpf.y, qlpf.z, qlpf.w};
        float qln[4] = {qlnf.x, qlnf.y, qlnf.z, qlnf.w};
        float qup[4] = {qupf.x, qupf.y, qupf.z, qupf.w};
        float qun[4] = {qunf.x, qunf.y, qunf.z, qunf.w};
#pragma unroll
        for (int e = 0; e < 4; e++) {
          const int idx = half * 4 + e;
          sv = fmaf(qv[e], kv[idx], sv);
          sl = fmaf(qlp[e], klp[idx], sl); sl = fmaf(qup[e], kln[idx], sl);
          sl = fmaf(qln[e], kup[idx], sl); sl = fmaf(qun[e], kun[idx], sl);
          su = fmaf(qup[e], kup[idx], su); su = fmaf(qlp[e], kun[idx], su);
          su = fmaf(qun[e], klp[idx], su); su = fmaf(qln[e], kln[idx], su);
        }
      }
#pragma unroll
      for (int m = 1; m <= 4; m <<= 1) {
        sv += __shfl_xor(sv, m, 64);
        sl += __shfl_xor(sl, m, 64);
        su += __shfl_xor(su, m, 64);
      }
      if (dgrp == 0) {
        s_v[q * 512 + c] = sv; s_l[q * 512 + c] = sl; s_u[q * 512 + c] = su;
      }
    }
  }
  __syncthreads();

  // ---- softmax bounds: one wave per row, rows wid and wid+4 ----
  const int lane = t & 63;
  const int wid  = t >> 6;
#pragma unroll
  for (int rr = 0; rr < 2; rr++) {
    const int r = wid + rr * 4;
    float mv = -1e30f, mu = -1e30f;
#pragma unroll
    for (int j = 0; j < 8; j++) {
      const int c = lane + j * 64;
      mv = fmaxf(mv, s_v[r * 512 + c]);
      mu = fmaxf(mu, s_u[r * 512 + c]);
    }
#pragma unroll
    for (int m = 1; m < 64; m <<= 1) {
      mv = fmaxf(mv, __shfl_xor(mv, m, 64));
      mu = fmaxf(mu, __shfl_xor(mu, m, 64));
    }
    float psv = 0.f, psl = 0.f, psu = 0.f;
#pragma unroll
    for (int j = 0; j < 8; j++) {
      const int c = r * 512 + lane + j * 64;
      const float ev = __expf(s_v[c] - mv);
      const float el = __expf(s_l[c] - mu);
      const float eu = __expf(s_u[c] - mu);
      s_v[c] = ev; s_l[c] = el; s_u[c] = eu;
      psv += ev; psl += el; psu += eu;
    }
#pragma unroll
    for (int m = 1; m < 64; m <<= 1) {
      psv += __shfl_xor(psv, m, 64);
      psl += __shfl_xor(psl, m, 64);
      psu += __shfl_xor(psu, m, 64);
    }
    const float rSv = 1.f / psv;
#pragma unroll
    for (int j = 0; j < 8; j++) {
      const int c = r * 512 + lane + j * 64;
      const float ev = s_v[c], el = s_l[c], eu = s_u[c];
      const float pv = ev * rSv;
      const float pl = el / (psu - eu + el);
      const float pu = eu / (psl - el + eu);
      s_v[c] = pv;
      s_l[c] = fminf(fmaxf(pl, 0.f), 1.f);
      s_u[c] = fminf(fmaxf(pu, 0.f), 1.f);
    }
  }
  __syncthreads();

  // ---- P @ V: thread owns (grp, d); V loaded+clamped once, reused x QT ----
  const int d   = t & 63;
  const int grp = t >> 6;
  float ov[QT], ol[QT], ou[QT];
#pragma unroll
  for (int q = 0; q < QT; q++) { ov[q] = 0.f; ol[q] = 0.f; ou[q] = 0.f; }
  const int vcol = 2048 + h * 64 + d;
  for (int j0 = 0; j0 < 128; j0 += 4) {
    float vvv[4], vlp[4], vln[4], vup[4], vun[4];
#pragma unroll
    for (int e = 0; e < 4; e++) {
      const int c  = grp * 128 + j0 + e;
      const int rv = (b * SEQ + c) * 3072 + vcol;
      const float vv_ = qkv_v[rv], vl_ = qkv_l[rv], vu_ = qkv_u[rv];
      vvv[e] = vv_;
      vlp[e] = fmaxf(vl_, 0.f); vln[e] = fminf(vl_, 0.f);
      vup[e] = fmaxf(vu_, 0.f); vun[e] = fminf(vu_, 0.f);
    }
#pragma unroll
    for (int q = 0; q < QT; q++) {
      const int base = q * 512 + grp * 128 + j0;
      float4 pv4 = *(const float4*)&s_v[base];
      float4 pl4 = *(const float4*)&s_l[base];
      float4 pu4 = *(const float4*)&s_u[base];
      float pv[4] = {pv4.x, pv4.y, pv4.z, pv4.w};
      float pl[4] = {pl4.x, pl4.y, pl4.z, pl4.w};
      float pu[4] = {pu4.x, pu4.y, pu4.z, pu4.w};
#pragma unroll
      for (int e = 0; e < 4; e++) {
        ov[q] = fmaf(pv[e], vvv[e], ov[q]);
        ol[q] = fmaf(pl[e], vlp[e], ol[q]); ol[q] = fmaf(pu[e], vln[e], ol[q]);
        ou[q] = fmaf(pu[e], vup[e], ou[q]); ou[q] = fmaf(pl[e], vun[e], ou[q]);
      }
    }
  }
  __syncthreads();   // all p reads done; smem can be reused

  // partials: part[grp][q][3][64]
  float* part = smem;
#pragma unroll
  for (int q = 0; q < QT; q++) {
    part[((grp * QT + q) * 3 + 0) * 64 + d] = ov[q];
    part[((grp * QT + q) * 3 + 1) * 64 + d] = ol[q];
    part[((grp * QT + q) * 3 + 2) * 64 + d] = ou[q];
  }
  __syncthreads();
  for (int i = t; i < QT * 64; i += 256) {
    const int q = i >> 6, dd = i & 63;
    float av = 0.f, al = 0.f, au = 0.f;
#pragma unroll
    for (int g = 0; g < 4; g++) {
      av += part[((g * QT + q) * 3 + 0) * 64 + dd];
      al += part[((g * QT + q) * 3 + 1) * 64 + dd];
      au += part[((g * QT + q) * 3 + 2) * 64 + dd];
    }
    const int ro = (b * SEQ + q0 + q) * 1024 + h * 64 + dd;
    o_v[ro] = av; o_l[ro] = al; o_u[ro] = au;
  }
}

// ---------------------------------------------------------------------------
extern "C" void kernel_launch(void* const* d_in, const int* in_sizes, int n_in,
                              void* d_out, int out_size, void* d_ws, size_t ws_size,
                              hipStream_t stream)
{
  const float* x_val = (const float*)d_in[0];
  const float* x_lb  = (const float*)d_in[1];
  const float* x_ub  = (const float*)d_in[2];
  const float* Wi    = (const float*)d_in[3];
  const float* bi    = (const float*)d_in[4];
  const float* Wo    = (const float*)d_in[5];
  const float* bo    = (const float*)d_in[6];
  float* out = (float*)d_out;

  float* ws    = (float*)d_ws;
  float* qkv_v = ws;
  float* qkv_l = qkv_v + (size_t)2048 * 3072;
  float* qkv_u = qkv_l + (size_t)2048 * 3072;
  float* ov    = qkv_u + (size_t)2048 * 3072;
  float* ol    = ov + (size_t)2048 * 1024;
  float* ou    = ol + (size_t)2048 * 1024;

  ibp_linear_kernel<<<dim3(3072 / 64, 2048 / 64), 256, 0, stream>>>(
      x_val, x_lb, x_ub, Wi, bi, qkv_v, qkv_l, qkv_u, 3072, 1024);

  ibp_attn_kernel<<<dim3(SEQ / QT, NHEAD, NBAT), 256, 0, stream>>>(
      qkv_v, qkv_l, qkv_u, ov, ol, ou);

  ibp_linear_kernel<<<dim3(1024 / 64, 2048 / 64), 256, 0, stream>>>(
      ov, ol, ou, Wo, bo,
      out, out + (size_t)2048 * 1024, out + (size_t)4096 * 1024, 1024, 1024);
}

// Round 3
// 1217.909 us; speedup vs baseline: 1.4453x; 1.1483x over previous
//
#include <hip/hip_runtime.h>
#include <math.h>

#define SEQ    512
#define EMB    1024
#define NHEAD  16
#define DHEAD  64
#define NBAT   4
#define QSCALE 0.125f   // 1/sqrt(64)
#define QT     8        // q-rows per attention block
#define PADK   40       // LDS row stride (ushorts) for 32-k tiles: 80 B -> conflict-free b128

typedef __attribute__((ext_vector_type(8))) short bf16x8;
typedef __attribute__((ext_vector_type(4))) float f32x4;

__device__ __forceinline__ unsigned short f2b(float x) {
  union { float f; unsigned int u; } a; a.f = x;
  unsigned int u = a.u;
  unsigned int r = (u + 0x7fffu + ((u >> 16) & 1u)) >> 16;   // round-nearest-even
  return (unsigned short)r;
}
__device__ __forceinline__ float b2f(unsigned short x) {
  union { unsigned int u; float f; } a; a.u = ((unsigned int)x) << 16; return a.f;
}

// ---------------------------------------------------------------------------
// convert v,l,u fp32 -> bf16 planes: outV[m][k]=v, outCR[m][k]=c, outCR[m][K+k]=r
// ---------------------------------------------------------------------------
__global__ __launch_bounds__(256)
void convert_stack(const float* __restrict__ v, const float* __restrict__ l,
                   const float* __restrict__ u,
                   unsigned short* __restrict__ outV,
                   unsigned short* __restrict__ outCR,
                   int K, int total4)
{
  int i = blockIdx.x * 256 + threadIdx.x;
  if (i >= total4) return;
  float4 v4 = ((const float4*)v)[i];
  float4 l4 = ((const float4*)l)[i];
  float4 u4 = ((const float4*)u)[i];
  const int K4 = K >> 2;
  const int m = i / K4, k4 = i - m * K4;
  float lv[4] = {l4.x, l4.y, l4.z, l4.w};
  float uv[4] = {u4.x, u4.y, u4.z, u4.w};
  float vv[4] = {v4.x, v4.y, v4.z, v4.w};
  ushort4 ov, oc, orr;
  unsigned short* pv = (unsigned short*)&ov;
  unsigned short* pc = (unsigned short*)&oc;
  unsigned short* pr = (unsigned short*)&orr;
#pragma unroll
  for (int e = 0; e < 4; e++) {
    pv[e] = f2b(vv[e]);
    pc[e] = f2b(0.5f * (lv[e] + uv[e]));
    pr[e] = f2b(0.5f * (uv[e] - lv[e]));
  }
  ((ushort4*)outV)[i] = ov;
  ((ushort4*)outCR)[(size_t)m * (K4 * 2) + k4]      = oc;
  ((ushort4*)outCR)[(size_t)m * (K4 * 2) + K4 + k4] = orr;
}

// ---------------------------------------------------------------------------
// W [K][N] fp32 -> Wt [N][K] bf16 and Wabs_t [N][K] bf16 (tiled transpose)
// ---------------------------------------------------------------------------
__global__ __launch_bounds__(256)
void wt_convert(const float* __restrict__ W,
                unsigned short* __restrict__ Wt,
                unsigned short* __restrict__ Wa, int K, int N)
{
  __shared__ float tile[32][33];
  const int n0 = blockIdx.x * 32, k0 = blockIdx.y * 32;
  const int tx = threadIdx.x, ty = threadIdx.y;   // 32 x 8
#pragma unroll
  for (int r = 0; r < 32; r += 8)
    tile[ty + r][tx] = W[(size_t)(k0 + ty + r) * N + n0 + tx];
  __syncthreads();
#pragma unroll
  for (int r = 0; r < 32; r += 8) {
    const float w = tile[tx][ty + r];   // = W[k0+tx][n0+ty+r]
    const size_t o = (size_t)(n0 + ty + r) * K + k0 + tx;
    Wt[o] = f2b(w);
    Wa[o] = f2b(fabsf(w));
  }
}

// ---------------------------------------------------------------------------
// bf16 GEMM, both operands k-major: C[m][n] = sum_k A[m][k] * B[n][k] (+bias)
// B is split at Ksplit: k < Ksplit reads B1 (stride Ksplit), else B2
// (stride Ktot-Ksplit), optionally negated (folds the -|W| half of the
// K-concatenated interval-linear lower bound). 128x128 tile, BK=32,
// 4 waves, 4x4 16x16x32 frags per wave. Output fp32 or bf16.
// ---------------------------------------------------------------------------
__global__ __launch_bounds__(256)
void gemm_bt_bf16(const unsigned short* __restrict__ A, int Ktot,
                  const unsigned short* __restrict__ B1,
                  const unsigned short* __restrict__ B2,
                  int Ksplit, int negB2,
                  const float* __restrict__ bias,
                  float* __restrict__ outF, unsigned short* __restrict__ outH,
                  int N)
{
  __shared__ __attribute__((aligned(16))) unsigned short As[128 * PADK];
  __shared__ __attribute__((aligned(16))) unsigned short Bs[128 * PADK];

  const int t    = threadIdx.x;
  const int m0   = blockIdx.y * 128, n0 = blockIdx.x * 128;
  const int lane = t & 63, w = t >> 6;
  const int wm   = w >> 1, wn = w & 1;
  const int quad = lane >> 4, r16 = lane & 15;

  f32x4 acc[4][4];
#pragma unroll
  for (int i = 0; i < 4; i++)
#pragma unroll
    for (int j = 0; j < 4; j++)
      acc[i][j] = (f32x4){0.f, 0.f, 0.f, 0.f};

  for (int k0 = 0; k0 < Ktot; k0 += 32) {
    const unsigned short* Bb;
    int kb, bstride;
    if (k0 < Ksplit) { Bb = B1; kb = k0; bstride = Ksplit; }
    else             { Bb = B2; kb = k0 - Ksplit; bstride = Ktot - Ksplit; }
    const bool neg = (negB2 != 0) && (k0 >= Ksplit);

    uint4 a_ld[2], b_ld[2];
#pragma unroll
    for (int rep = 0; rep < 2; rep++) {
      const int s = t + rep * 256, row = s >> 2, seg = s & 3;
      a_ld[rep] = *(const uint4*)(A + (size_t)(m0 + row) * Ktot + k0 + seg * 8);
      b_ld[rep] = *(const uint4*)(Bb + (size_t)(n0 + row) * bstride + kb + seg * 8);
    }
    if (neg) {
#pragma unroll
      for (int rep = 0; rep < 2; rep++) {
        b_ld[rep].x ^= 0x80008000u; b_ld[rep].y ^= 0x80008000u;
        b_ld[rep].z ^= 0x80008000u; b_ld[rep].w ^= 0x80008000u;
      }
    }
    __syncthreads();   // previous step's frag reads done
#pragma unroll
    for (int rep = 0; rep < 2; rep++) {
      const int s = t + rep * 256, row = s >> 2, seg = s & 3;
      *(uint4*)(As + row * PADK + seg * 8) = a_ld[rep];
      *(uint4*)(Bs + row * PADK + seg * 8) = b_ld[rep];
    }
    __syncthreads();

    bf16x8 af[4], bfr[4];
#pragma unroll
    for (int i = 0; i < 4; i++)
      af[i] = *(const bf16x8*)(As + (wm * 64 + i * 16 + r16) * PADK + quad * 8);
#pragma unroll
    for (int j = 0; j < 4; j++)
      bfr[j] = *(const bf16x8*)(Bs + (wn * 64 + j * 16 + r16) * PADK + quad * 8);
#pragma unroll
    for (int i = 0; i < 4; i++)
#pragma unroll
      for (int j = 0; j < 4; j++)
        acc[i][j] = __builtin_amdgcn_mfma_f32_16x16x32_bf16(af[i], bfr[j], acc[i][j], 0, 0, 0);
  }

  // epilogue: C/D layout col=lane&15, row=quad*4+reg
#pragma unroll
  for (int i = 0; i < 4; i++) {
#pragma unroll
    for (int j = 0; j < 4; j++) {
      const int n = n0 + wn * 64 + j * 16 + r16;
      const float bv = bias[n];
#pragma unroll
      for (int rI = 0; rI < 4; rI++) {
        const int m = m0 + wm * 64 + i * 16 + quad * 4 + rI;
        const float val = acc[i][j][rI] + bv;
        if (outH) outH[(size_t)m * N + n] = f2b(val);
        else      outF[(size_t)m * N + n] = val;
      }
    }
  }
}

// ---------------------------------------------------------------------------
// Fused IBP attention (bf16 qkv input), QT q-rows per block.
// ---------------------------------------------------------------------------
__global__ __launch_bounds__(256)
void ibp_attn_kernel(const unsigned short* __restrict__ qkv_v,
                     const unsigned short* __restrict__ qkv_l,
                     const unsigned short* __restrict__ qkv_u,
                     float* __restrict__ o_v,
                     float* __restrict__ o_l,
                     float* __restrict__ o_u)
{
  const int qblk = blockIdx.x;
  const int h    = blockIdx.y;
  const int b    = blockIdx.z;
  const int t    = threadIdx.x;
  const int q0   = qblk * QT;

  __shared__ __attribute__((aligned(16))) float smem[12288 + 2560];
  float* s_v = smem;
  float* s_l = smem + 4096;
  float* s_u = smem + 8192;
  float* qb  = smem + 12288;    // [5][QT*64]: qv, qlp, qln, qup, qun

  const int mq = b * SEQ + q0;

  for (int i = t; i < QT * 64; i += 256) {
    const int q = i >> 6, d = i & 63;
    const size_t gi = (size_t)(mq + q) * 3072 + h * 64 + d;
    const float qv = b2f(qkv_v[gi]) * QSCALE;
    const float ql = b2f(qkv_l[gi]) * QSCALE;
    const float qu = b2f(qkv_u[gi]) * QSCALE;
    qb[0 * 512 + i] = qv;
    qb[1 * 512 + i] = fmaxf(ql, 0.f);
    qb[2 * 512 + i] = fminf(ql, 0.f);
    qb[3 * 512 + i] = fmaxf(qu, 0.f);
    qb[4 * 512 + i] = fminf(qu, 0.f);
  }
  __syncthreads();

  const int cgrp = t >> 3;
  const int dgrp = t & 7;
  for (int it = 0; it < 16; it++) {
    const int c  = it * 32 + cgrp;
    const size_t rk = (size_t)(b * SEQ + c) * 3072 + 1024 + h * 64;
    float kv[8], klp[8], kln[8], kup[8], kun[8];
#pragma unroll
    for (int half = 0; half < 2; half++) {
      const int d = half * 32 + dgrp * 4;
      ushort4 kvf = *(const ushort4*)(qkv_v + rk + d);
      ushort4 klf = *(const ushort4*)(qkv_l + rk + d);
      ushort4 kuf = *(const ushort4*)(qkv_u + rk + d);
      const unsigned short* kvp = (const unsigned short*)&kvf;
      const unsigned short* klq = (const unsigned short*)&klf;
      const unsigned short* kuq = (const unsigned short*)&kuf;
#pragma unroll
      for (int e = 0; e < 4; e++) {
        const int idx = half * 4 + e;
        const float kvx = b2f(kvp[e]), klx = b2f(klq[e]), kux = b2f(kuq[e]);
        kv[idx]  = kvx;
        klp[idx] = fmaxf(klx, 0.f); kln[idx] = fminf(klx, 0.f);
        kup[idx] = fmaxf(kux, 0.f); kun[idx] = fminf(kux, 0.f);
      }
    }
#pragma unroll
    for (int q = 0; q < QT; q++) {
      float sv = 0.f, sl = 0.f, su = 0.f;
#pragma unroll
      for (int half = 0; half < 2; half++) {
        const int d = half * 32 + dgrp * 4;
        float4 qvf  = *(const float4*)&qb[0 * 512 + q * 64 + d];
        float4 qlpf = *(const float4*)&qb[1 * 512 + q * 64 + d];
        float4 qlnf = *(const float4*)&qb[2 * 512 + q * 64 + d];
        float4 qupf = *(const float4*)&qb[3 * 512 + q * 64 + d];
        float4 qunf = *(const float4*)&qb[4 * 512 + q * 64 + d];
        float qv_[4]  = {qvf.x, qvf.y, qvf.z, qvf.w};
        float qlp[4] = {qlpf.x, qlpf.y, qlpf.z, qlpf.w};
        float qln[4] = {qlnf.x, qlnf.y, qlnf.z, qlnf.w};
        float qup[4] = {qupf.x, qupf.y, qupf.z, qupf.w};
        float qun[4] = {qunf.x, qunf.y, qunf.z, qunf.w};
#pragma unroll
        for (int e = 0; e < 4; e++) {
          const int idx = half * 4 + e;
          sv = fmaf(qv_[e], kv[idx], sv);
          sl = fmaf(qlp[e], klp[idx], sl); sl = fmaf(qup[e], kln[idx], sl);
          sl = fmaf(qln[e], kup[idx], sl); sl = fmaf(qun[e], kun[idx], sl);
          su = fmaf(qup[e], kup[idx], su); su = fmaf(qlp[e], kun[idx], su);
          su = fmaf(qun[e], klp[idx], su); su = fmaf(qln[e], kln[idx], su);
        }
      }
#pragma unroll
      for (int m = 1; m <= 4; m <<= 1) {
        sv += __shfl_xor(sv, m, 64);
        sl += __shfl_xor(sl, m, 64);
        su += __shfl_xor(su, m, 64);
      }
      if (dgrp == 0) {
        s_v[q * 512 + c] = sv; s_l[q * 512 + c] = sl; s_u[q * 512 + c] = su;
      }
    }
  }
  __syncthreads();

  const int lane = t & 63;
  const int wid  = t >> 6;
#pragma unroll
  for (int rr = 0; rr < 2; rr++) {
    const int r = wid + rr * 4;
    float mv = -1e30f, mu = -1e30f;
#pragma unroll
    for (int j = 0; j < 8; j++) {
      const int c = lane + j * 64;
      mv = fmaxf(mv, s_v[r * 512 + c]);
      mu = fmaxf(mu, s_u[r * 512 + c]);
    }
#pragma unroll
    for (int m = 1; m < 64; m <<= 1) {
      mv = fmaxf(mv, __shfl_xor(mv, m, 64));
      mu = fmaxf(mu, __shfl_xor(mu, m, 64));
    }
    float psv = 0.f, psl = 0.f, psu = 0.f;
#pragma unroll
    for (int j = 0; j < 8; j++) {
      const int c = r * 512 + lane + j * 64;
      const float ev = __expf(s_v[c] - mv);
      const float el = __expf(s_l[c] - mu);
      const float eu = __expf(s_u[c] - mu);
      s_v[c] = ev; s_l[c] = el; s_u[c] = eu;
      psv += ev; psl += el; psu += eu;
    }
#pragma unroll
    for (int m = 1; m < 64; m <<= 1) {
      psv += __shfl_xor(psv, m, 64);
      psl += __shfl_xor(psl, m, 64);
      psu += __shfl_xor(psu, m, 64);
    }
    const float rSv = 1.f / psv;
#pragma unroll
    for (int j = 0; j < 8; j++) {
      const int c = r * 512 + lane + j * 64;
      const float ev = s_v[c], el = s_l[c], eu = s_u[c];
      const float pv = ev * rSv;
      const float pl = el / (psu - eu + el);
      const float pu = eu / (psl - el + eu);
      s_v[c] = pv;
      s_l[c] = fminf(fmaxf(pl, 0.f), 1.f);
      s_u[c] = fminf(fmaxf(pu, 0.f), 1.f);
    }
  }
  __syncthreads();

  const int d   = t & 63;
  const int grp = t >> 6;
  float ov[QT], ol[QT], ou[QT];
#pragma unroll
  for (int q = 0; q < QT; q++) { ov[q] = 0.f; ol[q] = 0.f; ou[q] = 0.f; }
  const int vcol = 2048 + h * 64 + d;
  for (int j0 = 0; j0 < 128; j0 += 4) {
    float vvv[4], vlp[4], vln[4], vup[4], vun[4];
#pragma unroll
    for (int e = 0; e < 4; e++) {
      const int c  = grp * 128 + j0 + e;
      const size_t rv = (size_t)(b * SEQ + c) * 3072 + vcol;
      const float vv_ = b2f(qkv_v[rv]);
      const float vl_ = b2f(qkv_l[rv]);
      const float vu_ = b2f(qkv_u[rv]);
      vvv[e] = vv_;
      vlp[e] = fmaxf(vl_, 0.f); vln[e] = fminf(vl_, 0.f);
      vup[e] = fmaxf(vu_, 0.f); vun[e] = fminf(vu_, 0.f);
    }
#pragma unroll
    for (int q = 0; q < QT; q++) {
      const int base = q * 512 + grp * 128 + j0;
      float4 pv4 = *(const float4*)&s_v[base];
      float4 pl4 = *(const float4*)&s_l[base];
      float4 pu4 = *(const float4*)&s_u[base];
      float pv[4] = {pv4.x, pv4.y, pv4.z, pv4.w};
      float pl[4] = {pl4.x, pl4.y, pl4.z, pl4.w};
      float pu[4] = {pu4.x, pu4.y, pu4.z, pu4.w};
#pragma unroll
      for (int e = 0; e < 4; e++) {
        ov[q] = fmaf(pv[e], vvv[e], ov[q]);
        ol[q] = fmaf(pl[e], vlp[e], ol[q]); ol[q] = fmaf(pu[e], vln[e], ol[q]);
        ou[q] = fmaf(pu[e], vup[e], ou[q]); ou[q] = fmaf(pl[e], vun[e], ou[q]);
      }
    }
  }
  __syncthreads();

  float* part = smem;
#pragma unroll
  for (int q = 0; q < QT; q++) {
    part[((grp * QT + q) * 3 + 0) * 64 + d] = ov[q];
    part[((grp * QT + q) * 3 + 1) * 64 + d] = ol[q];
    part[((grp * QT + q) * 3 + 2) * 64 + d] = ou[q];
  }
  __syncthreads();
  for (int i = t; i < QT * 64; i += 256) {
    const int q = i >> 6, dd = i & 63;
    float av = 0.f, al = 0.f, au = 0.f;
#pragma unroll
    for (int g = 0; g < 4; g++) {
      av += part[((g * QT + q) * 3 + 0) * 64 + dd];
      al += part[((g * QT + q) * 3 + 1) * 64 + dd];
      au += part[((g * QT + q) * 3 + 2) * 64 + dd];
    }
    const size_t ro = (size_t)(mq + q) * 1024 + h * 64 + dd;
    o_v[ro] = av; o_l[ro] = al; o_u[ro] = au;
  }
}

// ---------------------------------------------------------------------------
extern "C" void kernel_launch(void* const* d_in, const int* in_sizes, int n_in,
                              void* d_out, int out_size, void* d_ws, size_t ws_size,
                              hipStream_t stream)
{
  const float* x_val = (const float*)d_in[0];
  const float* x_lb  = (const float*)d_in[1];
  const float* x_ub  = (const float*)d_in[2];
  const float* Wi    = (const float*)d_in[3];
  const float* bi    = (const float*)d_in[4];
  const float* Wo    = (const float*)d_in[5];
  const float* bo    = (const float*)d_in[6];
  float* out = (float*)d_out;

  // ws layout (92.3 MB)
  char* p = (char*)d_ws;
  unsigned short* Xv  = (unsigned short*)p; p += (size_t)2048 * 1024 * 2;  // also Ov
  unsigned short* Xcr = (unsigned short*)p; p += (size_t)2048 * 2048 * 2;  // also Ocr
  unsigned short* Wit = (unsigned short*)p; p += (size_t)3072 * 1024 * 2;
  unsigned short* Wia = (unsigned short*)p; p += (size_t)3072 * 1024 * 2;
  unsigned short* Wot = (unsigned short*)p; p += (size_t)1024 * 1024 * 2;
  unsigned short* Woa = (unsigned short*)p; p += (size_t)1024 * 1024 * 2;
  unsigned short* qv  = (unsigned short*)p; p += (size_t)2048 * 3072 * 2;
  unsigned short* ql  = (unsigned short*)p; p += (size_t)2048 * 3072 * 2;
  unsigned short* qu  = (unsigned short*)p; p += (size_t)2048 * 3072 * 2;
  float* o_v = (float*)p; p += (size_t)2048 * 1024 * 4;
  float* o_l = (float*)p; p += (size_t)2048 * 1024 * 4;
  float* o_u = (float*)p; p += (size_t)2048 * 1024 * 4;

  // 1) convert inputs + weights to bf16 (weights k-major transposed, abs)
  convert_stack<<<2048, 256, 0, stream>>>(x_val, x_lb, x_ub, Xv, Xcr, 1024, 524288);
  wt_convert<<<dim3(96, 32), dim3(32, 8), 0, stream>>>(Wi, Wit, Wia, 1024, 3072);
  wt_convert<<<dim3(32, 32), dim3(32, 8), 0, stream>>>(Wo, Wot, Woa, 1024, 1024);

  // 2) in_proj: qv = Xv@W+b ; ql = Xc@W - Xr@|W| + b ; qu = Xc@W + Xr@|W| + b
  gemm_bt_bf16<<<dim3(24, 16), 256, 0, stream>>>(Xv, 1024, Wit, Wit, 1024, 0, bi, nullptr, qv, 3072);
  gemm_bt_bf16<<<dim3(24, 16), 256, 0, stream>>>(Xcr, 2048, Wit, Wia, 1024, 1, bi, nullptr, ql, 3072);
  gemm_bt_bf16<<<dim3(24, 16), 256, 0, stream>>>(Xcr, 2048, Wit, Wia, 1024, 0, bi, nullptr, qu, 3072);

  // 3) fused IBP attention
  ibp_attn_kernel<<<dim3(SEQ / QT, NHEAD, NBAT), 256, 0, stream>>>(qv, ql, qu, o_v, o_l, o_u);

  // 4) convert attention outputs, out_proj GEMMs -> [3,B,S,E] fp32
  convert_stack<<<2048, 256, 0, stream>>>(o_v, o_l, o_u, Xv, Xcr, 1024, 524288);
  gemm_bt_bf16<<<dim3(8, 16), 256, 0, stream>>>(Xv, 1024, Wot, Wot, 1024, 0, bo,
                                                out, nullptr, 1024);
  gemm_bt_bf16<<<dim3(8, 16), 256, 0, stream>>>(Xcr, 2048, Wot, Woa, 1024, 1, bo,
                                                out + (size_t)2048 * 1024, nullptr, 1024);
  gemm_bt_bf16<<<dim3(8, 16), 256, 0, stream>>>(Xcr, 2048, Wot, Woa, 1024, 0, bo,
                                                out + (size_t)4096 * 1024, nullptr, 1024);
}

// Round 4
// 821.189 us; speedup vs baseline: 2.1435x; 1.4831x over previous
//
#include <hip/hip_runtime.h>
#include <math.h>

#define SEQ    512
#define EMB    1024
#define NHEAD  16
#define DHEAD  64
#define NBAT   4
#define QSCALE 0.125f   // 1/sqrt(64)
#define QT     32       // q-rows per attention block
#define PADK   40       // GEMM LDS row stride (ushorts)

typedef __attribute__((ext_vector_type(8))) short bf16x8;
typedef __attribute__((ext_vector_type(4))) float f32x4;

#define MFMA16(a, b, c) __builtin_amdgcn_mfma_f32_16x16x32_bf16(a, b, c, 0, 0, 0)

__device__ __forceinline__ unsigned short f2b(float x) {
  union { float f; unsigned int u; } a; a.f = x;
  unsigned int u = a.u;
  unsigned int r = (u + 0x7fffu + ((u >> 16) & 1u)) >> 16;   // round-nearest-even
  return (unsigned short)r;
}
__device__ __forceinline__ float b2f(unsigned short x) {
  union { unsigned int u; float f; } a; a.u = ((unsigned int)x) << 16; return a.f;
}

// split bf16x8 into positive / negative parts (sign-bit select, exact)
__device__ __forceinline__ void clamp_pn8(bf16x8 x, bf16x8* p, bf16x8* n) {
  const unsigned short* xs = (const unsigned short*)&x;
  unsigned short* ps = (unsigned short*)p;
  unsigned short* ns = (unsigned short*)n;
#pragma unroll
  for (int e = 0; e < 8; e++) {
    const unsigned short s = xs[e] & 0x8000u;
    ps[e] = s ? (unsigned short)0 : xs[e];
    ns[e] = s ? xs[e] : (unsigned short)0;
  }
}

__device__ __forceinline__ float wave16_max(float x) {
#pragma unroll
  for (int m = 1; m <= 8; m <<= 1) x = fmaxf(x, __shfl_xor(x, m));
  return x;
}
__device__ __forceinline__ float wave16_sum(float x) {
#pragma unroll
  for (int m = 1; m <= 8; m <<= 1) x += __shfl_xor(x, m);
  return x;
}

// ---------------------------------------------------------------------------
// convert v,l,u fp32 -> bf16 planes: outV[m][k]=v, outCR[m][k]=c, outCR[m][K+k]=r
// ---------------------------------------------------------------------------
__global__ __launch_bounds__(256)
void convert_stack(const float* __restrict__ v, const float* __restrict__ l,
                   const float* __restrict__ u,
                   unsigned short* __restrict__ outV,
                   unsigned short* __restrict__ outCR,
                   int K, int total4)
{
  int i = blockIdx.x * 256 + threadIdx.x;
  if (i >= total4) return;
  float4 v4 = ((const float4*)v)[i];
  float4 l4 = ((const float4*)l)[i];
  float4 u4 = ((const float4*)u)[i];
  const int K4 = K >> 2;
  const int m = i / K4, k4 = i - m * K4;
  float lv[4] = {l4.x, l4.y, l4.z, l4.w};
  float uv[4] = {u4.x, u4.y, u4.z, u4.w};
  float vv[4] = {v4.x, v4.y, v4.z, v4.w};
  ushort4 ov, oc, orr;
  unsigned short* pv = (unsigned short*)&ov;
  unsigned short* pc = (unsigned short*)&oc;
  unsigned short* pr = (unsigned short*)&orr;
#pragma unroll
  for (int e = 0; e < 4; e++) {
    pv[e] = f2b(vv[e]);
    pc[e] = f2b(0.5f * (lv[e] + uv[e]));
    pr[e] = f2b(0.5f * (uv[e] - lv[e]));
  }
  ((ushort4*)outV)[i] = ov;
  ((ushort4*)outCR)[(size_t)m * (K4 * 2) + k4]      = oc;
  ((ushort4*)outCR)[(size_t)m * (K4 * 2) + K4 + k4] = orr;
}

// ---------------------------------------------------------------------------
// W [K][N] fp32 -> Wt [N][K] bf16 and Wabs_t [N][K] bf16 (tiled transpose)
// ---------------------------------------------------------------------------
__global__ __launch_bounds__(256)
void wt_convert(const float* __restrict__ W,
                unsigned short* __restrict__ Wt,
                unsigned short* __restrict__ Wa, int K, int N)
{
  __shared__ float tile[32][33];
  const int n0 = blockIdx.x * 32, k0 = blockIdx.y * 32;
  const int tx = threadIdx.x, ty = threadIdx.y;   // 32 x 8
#pragma unroll
  for (int r = 0; r < 32; r += 8)
    tile[ty + r][tx] = W[(size_t)(k0 + ty + r) * N + n0 + tx];
  __syncthreads();
#pragma unroll
  for (int r = 0; r < 32; r += 8) {
    const float w = tile[tx][ty + r];   // = W[k0+tx][n0+ty+r]
    const size_t o = (size_t)(n0 + ty + r) * K + k0 + tx;
    Wt[o] = f2b(w);
    Wa[o] = f2b(fabsf(w));
  }
}

// ---------------------------------------------------------------------------
// bf16 GEMM, both operands k-major (see R3 comments). 128x128 tile, BK=32.
// ---------------------------------------------------------------------------
__global__ __launch_bounds__(256)
void gemm_bt_bf16(const unsigned short* __restrict__ A, int Ktot,
                  const unsigned short* __restrict__ B1,
                  const unsigned short* __restrict__ B2,
                  int Ksplit, int negB2,
                  const float* __restrict__ bias,
                  float* __restrict__ outF, unsigned short* __restrict__ outH,
                  int N)
{
  __shared__ __attribute__((aligned(16))) unsigned short As[128 * PADK];
  __shared__ __attribute__((aligned(16))) unsigned short Bs[128 * PADK];

  const int t    = threadIdx.x;
  const int m0   = blockIdx.y * 128, n0 = blockIdx.x * 128;
  const int lane = t & 63, w = t >> 6;
  const int wm   = w >> 1, wn = w & 1;
  const int quad = lane >> 4, r16 = lane & 15;

  f32x4 acc[4][4];
#pragma unroll
  for (int i = 0; i < 4; i++)
#pragma unroll
    for (int j = 0; j < 4; j++)
      acc[i][j] = (f32x4){0.f, 0.f, 0.f, 0.f};

  for (int k0 = 0; k0 < Ktot; k0 += 32) {
    const unsigned short* Bb;
    int kb, bstride;
    if (k0 < Ksplit) { Bb = B1; kb = k0; bstride = Ksplit; }
    else             { Bb = B2; kb = k0 - Ksplit; bstride = Ktot - Ksplit; }
    const bool neg = (negB2 != 0) && (k0 >= Ksplit);

    uint4 a_ld[2], b_ld[2];
#pragma unroll
    for (int rep = 0; rep < 2; rep++) {
      const int s = t + rep * 256, row = s >> 2, seg = s & 3;
      a_ld[rep] = *(const uint4*)(A + (size_t)(m0 + row) * Ktot + k0 + seg * 8);
      b_ld[rep] = *(const uint4*)(Bb + (size_t)(n0 + row) * bstride + kb + seg * 8);
    }
    if (neg) {
#pragma unroll
      for (int rep = 0; rep < 2; rep++) {
        b_ld[rep].x ^= 0x80008000u; b_ld[rep].y ^= 0x80008000u;
        b_ld[rep].z ^= 0x80008000u; b_ld[rep].w ^= 0x80008000u;
      }
    }
    __syncthreads();
#pragma unroll
    for (int rep = 0; rep < 2; rep++) {
      const int s = t + rep * 256, row = s >> 2, seg = s & 3;
      *(uint4*)(As + row * PADK + seg * 8) = a_ld[rep];
      *(uint4*)(Bs + row * PADK + seg * 8) = b_ld[rep];
    }
    __syncthreads();

    bf16x8 af[4], bfr[4];
#pragma unroll
    for (int i = 0; i < 4; i++)
      af[i] = *(const bf16x8*)(As + (wm * 64 + i * 16 + r16) * PADK + quad * 8);
#pragma unroll
    for (int j = 0; j < 4; j++)
      bfr[j] = *(const bf16x8*)(Bs + (wn * 64 + j * 16 + r16) * PADK + quad * 8);
#pragma unroll
    for (int i = 0; i < 4; i++)
#pragma unroll
      for (int j = 0; j < 4; j++)
        acc[i][j] = MFMA16(af[i], bfr[j], acc[i][j]);
  }

#pragma unroll
  for (int i = 0; i < 4; i++) {
#pragma unroll
    for (int j = 0; j < 4; j++) {
      const int n = n0 + wn * 64 + j * 16 + r16;
      const float bv = bias[n];
#pragma unroll
      for (int rI = 0; rI < 4; rI++) {
        const int m = m0 + wm * 64 + i * 16 + quad * 4 + rI;
        const float val = acc[i][j][rI] + bv;
        if (outH) outH[(size_t)m * N + n] = f2b(val);
        else      outF[(size_t)m * N + n] = val;
      }
    }
  }
}

// ---------------------------------------------------------------------------
// V-part of qkv planes [2048][3072] (cols 2048..3071) -> Vt[bh][d][s] bf16
// ---------------------------------------------------------------------------
__global__ __launch_bounds__(256)
void v_transpose(const unsigned short* __restrict__ pv,
                 const unsigned short* __restrict__ pl,
                 const unsigned short* __restrict__ pu,
                 unsigned short* __restrict__ tv,
                 unsigned short* __restrict__ tl,
                 unsigned short* __restrict__ tu)
{
  __shared__ __attribute__((aligned(16))) unsigned short tile[64][72];
  const int stile = blockIdx.x;   // 0..7
  const int bh    = blockIdx.y;   // 0..63
  const int b = bh >> 4, h = bh & 15;
  const int c0 = stile * 64;
  const int t = threadIdx.x;
  const unsigned short* src[3] = {pv, pl, pu};
  unsigned short* dst[3] = {tv, tl, tu};
#pragma unroll
  for (int pI = 0; pI < 3; pI++) {
    if (pI) __syncthreads();
#pragma unroll
    for (int rep = 0; rep < 2; rep++) {
      const int unit = t + rep * 256, row = unit >> 3, seg = unit & 7;
      *(uint4*)&tile[row][seg * 8] =
          *(const uint4*)&src[pI][(size_t)(b * 512 + c0 + row) * 3072 + 2048 + h * 64 + seg * 8];
    }
    __syncthreads();
#pragma unroll
    for (int rep = 0; rep < 2; rep++) {
      const int unit = t + rep * 256, d = unit >> 3, seg = unit & 7;
      unsigned short tmp[8];
#pragma unroll
      for (int e = 0; e < 8; e++) tmp[e] = tile[seg * 8 + e][d];
      *(uint4*)&dst[pI][(size_t)(bh * 64 + d) * 512 + c0 + seg * 8] = *(uint4*)tmp;
    }
  }
}

// ---------------------------------------------------------------------------
// one 16x16 S sub-tile: 18 MFMA over K=64 (value 2, lb 8, ub 8)
// ---------------------------------------------------------------------------
__device__ __forceinline__ void qk_tile(const unsigned short* K0,
                                        const unsigned short* K1,
                                        const unsigned short* K2,
                                        int cl, int quad,
                                        const bf16x8 qvf[2], const bf16x8 qlpf[2],
                                        const bf16x8 qlnf[2], const bf16x8 qupf[2],
                                        const bf16x8 qunf[2],
                                        f32x4* avp, f32x4* alp, f32x4* aup)
{
  f32x4 v = {0.f, 0.f, 0.f, 0.f}, l = v, u = v;
#pragma unroll
  for (int kh = 0; kh < 2; kh++) {
    const int off = cl * 68 + kh * 32 + quad * 8;
    bf16x8 kv = *(const bf16x8*)(K0 + off);
    bf16x8 kl = *(const bf16x8*)(K1 + off);
    bf16x8 ku = *(const bf16x8*)(K2 + off);
    bf16x8 klp, kln, kup, kun;
    clamp_pn8(kl, &klp, &kln);
    clamp_pn8(ku, &kup, &kun);
    v = MFMA16(qvf[kh], kv, v);
    l = MFMA16(qlpf[kh], klp, l);
    l = MFMA16(qupf[kh], kln, l);
    l = MFMA16(qlnf[kh], kup, l);
    l = MFMA16(qunf[kh], kun, l);
    u = MFMA16(qupf[kh], kup, u);
    u = MFMA16(qlpf[kh], kun, u);
    u = MFMA16(qunf[kh], klp, u);
    u = MFMA16(qlnf[kh], kln, u);
  }
  *avp = v; *alp = l; *aup = u;
}

// ---------------------------------------------------------------------------
// MFMA IBP attention: block = (32 q-rows, h, b); 4 waves = 2 row-tiles x
// 2 col-halves. Pass 1: online row stats (m, sums) with S recompute-discard.
// Pass 2: recompute S, p -> LDS (bf16, A-layout), PV via MFMA.
// ---------------------------------------------------------------------------
__global__ __launch_bounds__(256, 2)
void ibp_attn_mfma(const unsigned short* __restrict__ qkv_v,
                   const unsigned short* __restrict__ qkv_l,
                   const unsigned short* __restrict__ qkv_u,
                   const unsigned short* __restrict__ vt_v,
                   const unsigned short* __restrict__ vt_l,
                   const unsigned short* __restrict__ vt_u,
                   float* __restrict__ o_v, float* __restrict__ o_l,
                   float* __restrict__ o_u)
{
  // pool: K tiles 3x[64][68], V tiles 3x[64][68], P 3x[32][68], stats 2x32x5 f32
  __shared__ __attribute__((aligned(16))) unsigned short pool[33280];
  unsigned short* Ks0 = pool;
  unsigned short* Ks1 = pool + 4352;
  unsigned short* Ks2 = pool + 8704;
  unsigned short* Vs0 = pool + 13056;
  unsigned short* Vs1 = pool + 17408;
  unsigned short* Vs2 = pool + 21760;
  unsigned short* Ps  = pool + 26112;           // [3][32][68], bound stride 2176
  float* st = (float*)(pool + 32640);           // [2][32][5]

  const int qblk = blockIdx.x, h = blockIdx.y, b = blockIdx.z;
  const int t = threadIdx.x, lane = t & 63, w = t >> 6;
  const int wm = w >> 1, wc = w & 1;
  const int quad = lane >> 4, r16 = lane & 15;
  const int mq = b * SEQ + qblk * QT;
  const int bh = b * NHEAD + h;

  // ---- Q fragments (A-layout: m=r16, k=quad*8+j), scaled + clamped ----
  bf16x8 qvf[2], qlpf[2], qlnf[2], qupf[2], qunf[2];
  {
    const size_t qrow = (size_t)(mq + wm * 16 + r16) * 3072 + h * 64;
#pragma unroll
    for (int kh = 0; kh < 2; kh++) {
      bf16x8 v8 = *(const bf16x8*)(qkv_v + qrow + kh * 32 + quad * 8);
      bf16x8 l8 = *(const bf16x8*)(qkv_l + qrow + kh * 32 + quad * 8);
      bf16x8 u8 = *(const bf16x8*)(qkv_u + qrow + kh * 32 + quad * 8);
      const unsigned short* vs = (const unsigned short*)&v8;
      const unsigned short* ls = (const unsigned short*)&l8;
      const unsigned short* us = (const unsigned short*)&u8;
      unsigned short* ov = (unsigned short*)&qvf[kh];
      unsigned short* lp = (unsigned short*)&qlpf[kh];
      unsigned short* ln = (unsigned short*)&qlnf[kh];
      unsigned short* up = (unsigned short*)&qupf[kh];
      unsigned short* un = (unsigned short*)&qunf[kh];
#pragma unroll
      for (int e = 0; e < 8; e++) {
        ov[e] = f2b(b2f(vs[e]) * QSCALE);
        const float lf = b2f(ls[e]) * QSCALE;
        const float uf = b2f(us[e]) * QSCALE;
        lp[e] = f2b(fmaxf(lf, 0.f)); ln[e] = f2b(fminf(lf, 0.f));
        up[e] = f2b(fmaxf(uf, 0.f)); un[e] = f2b(fminf(uf, 0.f));
      }
    }
  }

  float mv4[4], Sv4[4], mu4[4], Sl4[4], Su4[4];
#pragma unroll
  for (int r = 0; r < 4; r++) {
    mv4[r] = -1e30f; Sv4[r] = 0.f; mu4[r] = -1e30f; Sl4[r] = 0.f; Su4[r] = 0.f;
  }

  // ================= pass 1: row stats (online) =================
  for (int ct = 0; ct < 8; ct++) {
    const int c0 = ct * 64;
#pragma unroll
    for (int rep = 0; rep < 2; rep++) {
      const int unit = t + rep * 256, row = unit >> 3, seg = unit & 7;
      const size_t g = (size_t)(b * SEQ + c0 + row) * 3072 + 1024 + h * 64 + seg * 8;
      *(uint4*)(Ks0 + row * 68 + seg * 8) = *(const uint4*)(qkv_v + g);
      *(uint4*)(Ks1 + row * 68 + seg * 8) = *(const uint4*)(qkv_l + g);
      *(uint4*)(Ks2 + row * 68 + seg * 8) = *(const uint4*)(qkv_u + g);
    }
    __syncthreads();
#pragma unroll
    for (int sub = 0; sub < 2; sub++) {
      const int cl = wc * 32 + sub * 16 + r16;
      f32x4 av, al, au;
      qk_tile(Ks0, Ks1, Ks2, cl, quad, qvf, qlpf, qlnf, qupf, qunf, &av, &al, &au);
#pragma unroll
      for (int r = 0; r < 4; r++) {
        const float sv = av[r];
        const float mnew = fmaxf(mv4[r], wave16_max(sv));
        Sv4[r] = Sv4[r] * __expf(mv4[r] - mnew) + wave16_sum(__expf(sv - mnew));
        mv4[r] = mnew;

        const float suv = au[r], slv = al[r];
        const float mnu = fmaxf(mu4[r], wave16_max(suv));
        const float sc = __expf(mu4[r] - mnu);
        Su4[r] = Su4[r] * sc + wave16_sum(__expf(suv - mnu));
        Sl4[r] = Sl4[r] * sc + wave16_sum(__expf(slv - mnu));
        mu4[r] = mnu;
      }
    }
    __syncthreads();
  }

  // ---- merge stats across the two col-half waves ----
  if (r16 == 0) {
#pragma unroll
    for (int r = 0; r < 4; r++) {
      float* s = st + (wc * 32 + wm * 16 + quad * 4 + r) * 5;
      s[0] = mv4[r]; s[1] = Sv4[r]; s[2] = mu4[r]; s[3] = Sl4[r]; s[4] = Su4[r];
    }
  }
  __syncthreads();
  float rSv4[4];
#pragma unroll
  for (int r = 0; r < 4; r++) {
    const int row = wm * 16 + quad * 4 + r;
    const float* s0 = st + row * 5;
    const float* s1 = st + (32 + row) * 5;
    const float mv = fmaxf(s0[0], s1[0]);
    const float Sv = s0[1] * __expf(s0[0] - mv) + s1[1] * __expf(s1[0] - mv);
    const float mu = fmaxf(s0[2], s1[2]);
    const float e0 = __expf(s0[2] - mu), e1 = __expf(s1[2] - mu);
    mv4[r] = mv; rSv4[r] = 1.f / Sv; mu4[r] = mu;
    Sl4[r] = s0[3] * e0 + s1[3] * e1;
    Su4[r] = s0[4] * e0 + s1[4] * e1;
  }
  __syncthreads();

  // ================= pass 2: p and P@V =================
  f32x4 oa[3][4];
#pragma unroll
  for (int bo = 0; bo < 3; bo++)
#pragma unroll
    for (int ds = 0; ds < 4; ds++) oa[bo][ds] = (f32x4){0.f, 0.f, 0.f, 0.f};

  for (int ct = 0; ct < 8; ct++) {
    const int c0 = ct * 64;
#pragma unroll
    for (int rep = 0; rep < 2; rep++) {
      const int unit = t + rep * 256, row = unit >> 3, seg = unit & 7;
      const size_t gk = (size_t)(b * SEQ + c0 + row) * 3072 + 1024 + h * 64 + seg * 8;
      *(uint4*)(Ks0 + row * 68 + seg * 8) = *(const uint4*)(qkv_v + gk);
      *(uint4*)(Ks1 + row * 68 + seg * 8) = *(const uint4*)(qkv_l + gk);
      *(uint4*)(Ks2 + row * 68 + seg * 8) = *(const uint4*)(qkv_u + gk);
      const size_t gv = (size_t)(bh * 64 + row) * 512 + c0 + seg * 8;
      *(uint4*)(Vs0 + row * 68 + seg * 8) = *(const uint4*)(vt_v + gv);
      *(uint4*)(Vs1 + row * 68 + seg * 8) = *(const uint4*)(vt_l + gv);
      *(uint4*)(Vs2 + row * 68 + seg * 8) = *(const uint4*)(vt_u + gv);
    }
    __syncthreads();
#pragma unroll
    for (int sub = 0; sub < 2; sub++) {
      const int cl = wc * 32 + sub * 16 + r16;
      f32x4 av, al, au;
      qk_tile(Ks0, Ks1, Ks2, cl, quad, qvf, qlpf, qlnf, qupf, qunf, &av, &al, &au);
#pragma unroll
      for (int r = 0; r < 4; r++) {
        const int mloc = wm * 16 + quad * 4 + r;
        const float pv = __expf(av[r] - mv4[r]) * rSv4[r];
        const float el = __expf(al[r] - mu4[r]);
        const float eu = __expf(au[r] - mu4[r]);
        float pl = el / (Su4[r] - eu + el);
        float pu = eu / (Sl4[r] - el + eu);
        pl = fminf(fmaxf(pl, 0.f), 1.f);
        pu = fminf(fmaxf(pu, 0.f), 1.f);
        Ps[0 * 2176 + mloc * 68 + cl] = f2b(pv);
        Ps[1 * 2176 + mloc * 68 + cl] = f2b(pl);
        Ps[2 * 2176 + mloc * 68 + cl] = f2b(pu);
      }
    }
    __syncthreads();
#pragma unroll
    for (int dsub = 0; dsub < 4; dsub++) {
      const int voff = (dsub * 16 + r16) * 68 + wc * 32 + quad * 8;
      bf16x8 vv = *(const bf16x8*)(Vs0 + voff);
      bf16x8 vl = *(const bf16x8*)(Vs1 + voff);
      bf16x8 vu = *(const bf16x8*)(Vs2 + voff);
      bf16x8 vlp, vln, vup, vun;
      clamp_pn8(vl, &vlp, &vln);
      clamp_pn8(vu, &vup, &vun);
      const int arow = (wm * 16 + r16) * 68 + wc * 32 + quad * 8;
      bf16x8 pav = *(const bf16x8*)(Ps + 0 * 2176 + arow);
      bf16x8 pal = *(const bf16x8*)(Ps + 1 * 2176 + arow);
      bf16x8 pau = *(const bf16x8*)(Ps + 2 * 2176 + arow);
      oa[0][dsub] = MFMA16(pav, vv, oa[0][dsub]);
      oa[1][dsub] = MFMA16(pal, vlp, oa[1][dsub]);
      oa[1][dsub] = MFMA16(pau, vln, oa[1][dsub]);
      oa[2][dsub] = MFMA16(pau, vup, oa[2][dsub]);
      oa[2][dsub] = MFMA16(pal, vun, oa[2][dsub]);
    }
    __syncthreads();
  }

  // ---- reduce the two col-half waves, store ----
  float* obuf = (float*)pool;   // 24576 B, aliases K/V tiles (done with them)
  if (wc == 1) {
#pragma unroll
    for (int bo = 0; bo < 3; bo++)
#pragma unroll
      for (int dsub = 0; dsub < 4; dsub++)
#pragma unroll
        for (int r = 0; r < 4; r++)
          obuf[((wm * 3 + bo) * 16 + quad * 4 + r) * 64 + dsub * 16 + r16] = oa[bo][dsub][r];
  }
  __syncthreads();
  if (wc == 0) {
    float* outp[3] = {o_v, o_l, o_u};
#pragma unroll
    for (int bo = 0; bo < 3; bo++)
#pragma unroll
      for (int dsub = 0; dsub < 4; dsub++)
#pragma unroll
        for (int r = 0; r < 4; r++) {
          const float vsum = oa[bo][dsub][r] +
              obuf[((wm * 3 + bo) * 16 + quad * 4 + r) * 64 + dsub * 16 + r16];
          outp[bo][(size_t)(mq + wm * 16 + quad * 4 + r) * 1024 + h * 64 + dsub * 16 + r16] = vsum;
        }
  }
}

// ---------------------------------------------------------------------------
extern "C" void kernel_launch(void* const* d_in, const int* in_sizes, int n_in,
                              void* d_out, int out_size, void* d_ws, size_t ws_size,
                              hipStream_t stream)
{
  const float* x_val = (const float*)d_in[0];
  const float* x_lb  = (const float*)d_in[1];
  const float* x_ub  = (const float*)d_in[2];
  const float* Wi    = (const float*)d_in[3];
  const float* bi    = (const float*)d_in[4];
  const float* Wo    = (const float*)d_in[5];
  const float* bo    = (const float*)d_in[6];
  float* out = (float*)d_out;

  // ws layout (92.3 MB). Vt planes alias Xv/Xcr (dead during attention).
  char* p = (char*)d_ws;
  unsigned short* Xv  = (unsigned short*)p; p += (size_t)2048 * 1024 * 2;  // also Ov, Vt_v
  unsigned short* Xcr = (unsigned short*)p; p += (size_t)2048 * 2048 * 2;  // also Ocr, Vt_l/u
  unsigned short* Wit = (unsigned short*)p; p += (size_t)3072 * 1024 * 2;
  unsigned short* Wia = (unsigned short*)p; p += (size_t)3072 * 1024 * 2;
  unsigned short* Wot = (unsigned short*)p; p += (size_t)1024 * 1024 * 2;
  unsigned short* Woa = (unsigned short*)p; p += (size_t)1024 * 1024 * 2;
  unsigned short* qv  = (unsigned short*)p; p += (size_t)2048 * 3072 * 2;
  unsigned short* ql  = (unsigned short*)p; p += (size_t)2048 * 3072 * 2;
  unsigned short* qu  = (unsigned short*)p; p += (size_t)2048 * 3072 * 2;
  float* o_v = (float*)p; p += (size_t)2048 * 1024 * 4;
  float* o_l = (float*)p; p += (size_t)2048 * 1024 * 4;
  float* o_u = (float*)p; p += (size_t)2048 * 1024 * 4;

  unsigned short* Vtv = Xv;                               // [64][64][512] bf16
  unsigned short* Vtl = Xv + (size_t)64 * 64 * 512;
  unsigned short* Vtu = Xv + (size_t)2 * 64 * 64 * 512;

  // 1) convert inputs + weights to bf16
  convert_stack<<<2048, 256, 0, stream>>>(x_val, x_lb, x_ub, Xv, Xcr, 1024, 524288);
  wt_convert<<<dim3(96, 32), dim3(32, 8), 0, stream>>>(Wi, Wit, Wia, 1024, 3072);
  wt_convert<<<dim3(32, 32), dim3(32, 8), 0, stream>>>(Wo, Wot, Woa, 1024, 1024);

  // 2) in_proj GEMMs
  gemm_bt_bf16<<<dim3(24, 16), 256, 0, stream>>>(Xv, 1024, Wit, Wit, 1024, 0, bi, nullptr, qv, 3072);
  gemm_bt_bf16<<<dim3(24, 16), 256, 0, stream>>>(Xcr, 2048, Wit, Wia, 1024, 1, bi, nullptr, ql, 3072);
  gemm_bt_bf16<<<dim3(24, 16), 256, 0, stream>>>(Xcr, 2048, Wit, Wia, 1024, 0, bi, nullptr, qu, 3072);

  // 3) V transpose (Xv/Xcr now dead -> reuse as Vt)
  v_transpose<<<dim3(8, 64), 256, 0, stream>>>(qv, ql, qu, Vtv, Vtl, Vtu);

  // 4) MFMA IBP attention
  ibp_attn_mfma<<<dim3(SEQ / QT, NHEAD, NBAT), 256, 0, stream>>>(
      qv, ql, qu, Vtv, Vtl, Vtu, o_v, o_l, o_u);

  // 5) out_proj
  convert_stack<<<2048, 256, 0, stream>>>(o_v, o_l, o_u, Xv, Xcr, 1024, 524288);
  gemm_bt_bf16<<<dim3(8, 16), 256, 0, stream>>>(Xv, 1024, Wot, Wot, 1024, 0, bo,
                                                out, nullptr, 1024);
  gemm_bt_bf16<<<dim3(8, 16), 256, 0, stream>>>(Xcr, 2048, Wot, Woa, 1024, 1, bo,
                                                out + (size_t)2048 * 1024, nullptr, 1024);
  gemm_bt_bf16<<<dim3(8, 16), 256, 0, stream>>>(Xcr, 2048, Wot, Woa, 1024, 0, bo,
                                                out + (size_t)4096 * 1024, nullptr, 1024);
}

// Round 5
// 712.282 us; speedup vs baseline: 2.4713x; 1.1529x over previous
//
#include <hip/hip_runtime.h>
#include <math.h>

#define SEQ    512
#define EMB    1024
#define NHEAD  16
#define DHEAD  64
#define NBAT   4
#define QSCALE 0.125f   // 1/sqrt(64)
#define PADK   40       // GEMM LDS row stride (ushorts)
#define KST    68       // attn LDS row stride (ushorts): 136B rows, frag reads <=2-way banks

typedef __attribute__((ext_vector_type(8))) short bf16x8;
typedef __attribute__((ext_vector_type(4))) float f32x4;

#define MFMA16(a, b, c) __builtin_amdgcn_mfma_f32_16x16x32_bf16(a, b, c, 0, 0, 0)

__device__ __forceinline__ unsigned short f2b(float x) {
  union { float f; unsigned int u; } a; a.f = x;
  unsigned int u = a.u;
  unsigned int r = (u + 0x7fffu + ((u >> 16) & 1u)) >> 16;   // RNE
  return (unsigned short)r;
}
__device__ __forceinline__ unsigned short f2b_fast(float x) {
  union { float f; unsigned int u; } a; a.f = x;
  return (unsigned short)((a.u + 0x8000u) >> 16);            // round-half-up, 2 ops
}
__device__ __forceinline__ float b2f(unsigned short x) {
  union { unsigned int u; float f; } a; a.u = ((unsigned int)x) << 16; return a.f;
}

// packed sign-based split of bf16x8 into positive/negative parts (exact)
__device__ __forceinline__ void clamp_pn8(bf16x8 x, bf16x8* p, bf16x8* n) {
  const unsigned int* xu = (const unsigned int*)&x;
  unsigned int* pp = (unsigned int*)p;
  unsigned int* nn = (unsigned int*)n;
#pragma unroll
  for (int e = 0; e < 4; e++) {
    const unsigned int s = xu[e] & 0x80008000u;
    const unsigned int mask = s | (s - (s >> 15));   // 0xFFFF in negative halves
    nn[e] = xu[e] & mask;
    pp[e] = xu[e] & ~mask;
  }
}

__device__ __forceinline__ float wave16_sum(float x) {
#pragma unroll
  for (int m = 1; m <= 8; m <<= 1) x += __shfl_xor(x, m);
  return x;
}

// ---------------------------------------------------------------------------
// convert v,l,u fp32 -> bf16 planes: outV[m][k]=v, outCR[m][k]=c, outCR[m][K+k]=r
// ---------------------------------------------------------------------------
__global__ __launch_bounds__(256)
void convert_stack(const float* __restrict__ v, const float* __restrict__ l,
                   const float* __restrict__ u,
                   unsigned short* __restrict__ outV,
                   unsigned short* __restrict__ outCR,
                   int K, int total4)
{
  int i = blockIdx.x * 256 + threadIdx.x;
  if (i >= total4) return;
  float4 v4 = ((const float4*)v)[i];
  float4 l4 = ((const float4*)l)[i];
  float4 u4 = ((const float4*)u)[i];
  const int K4 = K >> 2;
  const int m = i / K4, k4 = i - m * K4;
  float lv[4] = {l4.x, l4.y, l4.z, l4.w};
  float uv[4] = {u4.x, u4.y, u4.z, u4.w};
  float vv[4] = {v4.x, v4.y, v4.z, v4.w};
  ushort4 ov, oc, orr;
  unsigned short* pv = (unsigned short*)&ov;
  unsigned short* pc = (unsigned short*)&oc;
  unsigned short* pr = (unsigned short*)&orr;
#pragma unroll
  for (int e = 0; e < 4; e++) {
    pv[e] = f2b(vv[e]);
    pc[e] = f2b(0.5f * (lv[e] + uv[e]));
    pr[e] = f2b(0.5f * (uv[e] - lv[e]));
  }
  ((ushort4*)outV)[i] = ov;
  ((ushort4*)outCR)[(size_t)m * (K4 * 2) + k4]      = oc;
  ((ushort4*)outCR)[(size_t)m * (K4 * 2) + K4 + k4] = orr;
}

// ---------------------------------------------------------------------------
// W [K][N] fp32 -> Wt [N][K] bf16 and Wabs_t [N][K] bf16 (tiled transpose)
// ---------------------------------------------------------------------------
__global__ __launch_bounds__(256)
void wt_convert(const float* __restrict__ W,
                unsigned short* __restrict__ Wt,
                unsigned short* __restrict__ Wa, int K, int N)
{
  __shared__ float tile[32][33];
  const int n0 = blockIdx.x * 32, k0 = blockIdx.y * 32;
  const int tx = threadIdx.x, ty = threadIdx.y;   // 32 x 8
#pragma unroll
  for (int r = 0; r < 32; r += 8)
    tile[ty + r][tx] = W[(size_t)(k0 + ty + r) * N + n0 + tx];
  __syncthreads();
#pragma unroll
  for (int r = 0; r < 32; r += 8) {
    const float w = tile[tx][ty + r];
    const size_t o = (size_t)(n0 + ty + r) * K + k0 + tx;
    Wt[o] = f2b(w);
    Wa[o] = f2b(fabsf(w));
  }
}

// ---------------------------------------------------------------------------
// bf16 GEMM, both operands k-major (see R3 comments). 128x128 tile, BK=32.
// ---------------------------------------------------------------------------
__global__ __launch_bounds__(256)
void gemm_bt_bf16(const unsigned short* __restrict__ A, int Ktot,
                  const unsigned short* __restrict__ B1,
                  const unsigned short* __restrict__ B2,
                  int Ksplit, int negB2,
                  const float* __restrict__ bias,
                  float* __restrict__ outF, unsigned short* __restrict__ outH,
                  int N)
{
  __shared__ __attribute__((aligned(16))) unsigned short As[128 * PADK];
  __shared__ __attribute__((aligned(16))) unsigned short Bs[128 * PADK];

  const int t    = threadIdx.x;
  const int m0   = blockIdx.y * 128, n0 = blockIdx.x * 128;
  const int lane = t & 63, w = t >> 6;
  const int wm   = w >> 1, wn = w & 1;
  const int quad = lane >> 4, r16 = lane & 15;

  f32x4 acc[4][4];
#pragma unroll
  for (int i = 0; i < 4; i++)
#pragma unroll
    for (int j = 0; j < 4; j++)
      acc[i][j] = (f32x4){0.f, 0.f, 0.f, 0.f};

  for (int k0 = 0; k0 < Ktot; k0 += 32) {
    const unsigned short* Bb;
    int kb, bstride;
    if (k0 < Ksplit) { Bb = B1; kb = k0; bstride = Ksplit; }
    else             { Bb = B2; kb = k0 - Ksplit; bstride = Ktot - Ksplit; }
    const bool neg = (negB2 != 0) && (k0 >= Ksplit);

    uint4 a_ld[2], b_ld[2];
#pragma unroll
    for (int rep = 0; rep < 2; rep++) {
      const int s = t + rep * 256, row = s >> 2, seg = s & 3;
      a_ld[rep] = *(const uint4*)(A + (size_t)(m0 + row) * Ktot + k0 + seg * 8);
      b_ld[rep] = *(const uint4*)(Bb + (size_t)(n0 + row) * bstride + kb + seg * 8);
    }
    if (neg) {
#pragma unroll
      for (int rep = 0; rep < 2; rep++) {
        b_ld[rep].x ^= 0x80008000u; b_ld[rep].y ^= 0x80008000u;
        b_ld[rep].z ^= 0x80008000u; b_ld[rep].w ^= 0x80008000u;
      }
    }
    __syncthreads();
#pragma unroll
    for (int rep = 0; rep < 2; rep++) {
      const int s = t + rep * 256, row = s >> 2, seg = s & 3;
      *(uint4*)(As + row * PADK + seg * 8) = a_ld[rep];
      *(uint4*)(Bs + row * PADK + seg * 8) = b_ld[rep];
    }
    __syncthreads();

    bf16x8 af[4], bfr[4];
#pragma unroll
    for (int i = 0; i < 4; i++)
      af[i] = *(const bf16x8*)(As + (wm * 64 + i * 16 + r16) * PADK + quad * 8);
#pragma unroll
    for (int j = 0; j < 4; j++)
      bfr[j] = *(const bf16x8*)(Bs + (wn * 64 + j * 16 + r16) * PADK + quad * 8);
#pragma unroll
    for (int i = 0; i < 4; i++)
#pragma unroll
      for (int j = 0; j < 4; j++)
        acc[i][j] = MFMA16(af[i], bfr[j], acc[i][j]);
  }

#pragma unroll
  for (int i = 0; i < 4; i++) {
#pragma unroll
    for (int j = 0; j < 4; j++) {
      const int n = n0 + wn * 64 + j * 16 + r16;
      const float bv = bias[n];
#pragma unroll
      for (int rI = 0; rI < 4; rI++) {
        const int m = m0 + wm * 64 + i * 16 + quad * 4 + rI;
        const float val = acc[i][j][rI] + bv;
        if (outH) outH[(size_t)m * N + n] = f2b(val);
        else      outF[(size_t)m * N + n] = val;
      }
    }
  }
}

// ---------------------------------------------------------------------------
// V-part of qkv planes [2048][3072] (cols 2048..3071) -> Vt[bh][d][s] bf16
// ---------------------------------------------------------------------------
__global__ __launch_bounds__(256)
void v_transpose(const unsigned short* __restrict__ pv,
                 const unsigned short* __restrict__ pl,
                 const unsigned short* __restrict__ pu,
                 unsigned short* __restrict__ tv,
                 unsigned short* __restrict__ tl,
                 unsigned short* __restrict__ tu)
{
  __shared__ __attribute__((aligned(16))) unsigned short tile[64][72];
  const int stile = blockIdx.x;   // 0..7
  const int bh    = blockIdx.y;   // 0..63
  const int b = bh >> 4, h = bh & 15;
  const int c0 = stile * 64;
  const int t = threadIdx.x;
  const unsigned short* src[3] = {pv, pl, pu};
  unsigned short* dst[3] = {tv, tl, tu};
#pragma unroll
  for (int pI = 0; pI < 3; pI++) {
    if (pI) __syncthreads();
#pragma unroll
    for (int rep = 0; rep < 2; rep++) {
      const int unit = t + rep * 256, row = unit >> 3, seg = unit & 7;
      *(uint4*)&tile[row][seg * 8] =
          *(const uint4*)&src[pI][(size_t)(b * 512 + c0 + row) * 3072 + 2048 + h * 64 + seg * 8];
    }
    __syncthreads();
#pragma unroll
    for (int rep = 0; rep < 2; rep++) {
      const int unit = t + rep * 256, d = unit >> 3, seg = unit & 7;
      unsigned short tmp[8];
#pragma unroll
      for (int e = 0; e < 8; e++) tmp[e] = tile[seg * 8 + e][d];
      *(uint4*)&dst[pI][(size_t)(bh * 64 + d) * 512 + c0 + seg * 8] = *(uint4*)tmp;
    }
  }
}

// ---------------------------------------------------------------------------
// one 16x16 S sub-tile (col block cl0 + r16): 18 MFMA over K=64
// ---------------------------------------------------------------------------
__device__ __forceinline__ void qk_tile(const unsigned short* K0,
                                        const unsigned short* K1,
                                        const unsigned short* K2,
                                        int cl, int quad,
                                        const bf16x8 qvf[2], const bf16x8 qlpf[2],
                                        const bf16x8 qlnf[2], const bf16x8 qupf[2],
                                        const bf16x8 qunf[2],
                                        f32x4* avp, f32x4* alp, f32x4* aup)
{
  f32x4 v = {0.f, 0.f, 0.f, 0.f}, l = v, u = v;
#pragma unroll
  for (int kh = 0; kh < 2; kh++) {
    const int off = cl * KST + kh * 32 + quad * 8;
    bf16x8 kv = *(const bf16x8*)(K0 + off);
    bf16x8 kl = *(const bf16x8*)(K1 + off);
    bf16x8 ku = *(const bf16x8*)(K2 + off);
    bf16x8 klp, kln, kup, kun;
    clamp_pn8(kl, &klp, &kln);
    clamp_pn8(ku, &kup, &kun);
    v = MFMA16(qvf[kh], kv, v);
    l = MFMA16(qlpf[kh], klp, l);
    l = MFMA16(qupf[kh], kln, l);
    l = MFMA16(qlnf[kh], kup, l);
    l = MFMA16(qunf[kh], kun, l);
    u = MFMA16(qupf[kh], kup, u);
    u = MFMA16(qlpf[kh], kun, u);
    u = MFMA16(qunf[kh], klp, u);
    u = MFMA16(qlnf[kh], kln, u);
  }
  *avp = v; *alp = l; *aup = u;
}

// ---------------------------------------------------------------------------
// MFMA IBP attention v2: block = 64 q-rows x (b,h); 4 independent waves, each
// owns a 16-row stripe across ALL columns. No max-subtraction (|s| small),
// no online rescale, no cross-wave merges. pv denominator folded into epilogue.
// Pass 1: raw exp-sums (ping-pong K staging). Pass 2: recompute S, p -> own
// LDS stripe (no barrier), PV via MFMA.
// ---------------------------------------------------------------------------
__global__ __launch_bounds__(256, 2)
void ibp_attn_mfma(const unsigned short* __restrict__ qkv_v,
                   const unsigned short* __restrict__ qkv_l,
                   const unsigned short* __restrict__ qkv_u,
                   const unsigned short* __restrict__ vt_v,
                   const unsigned short* __restrict__ vt_l,
                   const unsigned short* __restrict__ vt_u,
                   float* __restrict__ o_v, float* __restrict__ o_l,
                   float* __restrict__ o_u)
{
  // pool (ushorts): K planes 3x[64][KST], V planes 3x[64][KST], P 3x[64][KST]
  __shared__ __attribute__((aligned(16))) unsigned short pool[9 * 64 * KST];
  unsigned short* Ks = pool;                 // 3 planes, stride 64*KST each
  unsigned short* Vs = pool + 3 * 64 * KST;  // 3 planes (pass-1 ping-pong buf B)
  unsigned short* Ps = pool + 6 * 64 * KST;  // 3 planes

  const int qblk = blockIdx.x, h = blockIdx.y, b = blockIdx.z;
  const int t = threadIdx.x, lane = t & 63, w = t >> 6;
  const int quad = lane >> 4, r16 = lane & 15;
  const int row0 = w * 16;                   // wave's q-row stripe in block
  const int mq = b * SEQ + qblk * 64;
  const int bh = b * NHEAD + h;
  const int PL = 64 * KST;                   // plane stride

  // ---- Q fragments (A-layout: m=r16, k=quad*8+j), scaled + clamped ----
  bf16x8 qvf[2], qlpf[2], qlnf[2], qupf[2], qunf[2];
  {
    const size_t qrow = (size_t)(mq + row0 + r16) * 3072 + h * 64;
#pragma unroll
    for (int kh = 0; kh < 2; kh++) {
      bf16x8 v8 = *(const bf16x8*)(qkv_v + qrow + kh * 32 + quad * 8);
      bf16x8 l8 = *(const bf16x8*)(qkv_l + qrow + kh * 32 + quad * 8);
      bf16x8 u8 = *(const bf16x8*)(qkv_u + qrow + kh * 32 + quad * 8);
      const unsigned short* vs = (const unsigned short*)&v8;
      const unsigned short* ls = (const unsigned short*)&l8;
      const unsigned short* us = (const unsigned short*)&u8;
      unsigned short* ov = (unsigned short*)&qvf[kh];
      unsigned short* lp = (unsigned short*)&qlpf[kh];
      unsigned short* ln = (unsigned short*)&qlnf[kh];
      unsigned short* up = (unsigned short*)&qupf[kh];
      unsigned short* un = (unsigned short*)&qunf[kh];
#pragma unroll
      for (int e = 0; e < 8; e++) {
        ov[e] = f2b(b2f(vs[e]) * QSCALE);
        const float lf = b2f(ls[e]) * QSCALE;
        const float uf = b2f(us[e]) * QSCALE;
        lp[e] = f2b(fmaxf(lf, 0.f)); ln[e] = f2b(fminf(lf, 0.f));
        up[e] = f2b(fmaxf(uf, 0.f)); un[e] = f2b(fminf(uf, 0.f));
      }
    }
  }

  // ================= pass 1: raw exp row-sums =================
  float Svp[4] = {0.f, 0.f, 0.f, 0.f};
  float Slp[4] = {0.f, 0.f, 0.f, 0.f};
  float Sup[4] = {0.f, 0.f, 0.f, 0.f};

  // ping-pong K staging between Ks and Vs regions
  {
    // stage ct=0 into Ks
#pragma unroll
    for (int rep = 0; rep < 2; rep++) {
      const int unit = t + rep * 256, row = unit >> 3, seg = unit & 7;
      const size_t g = (size_t)(b * SEQ + row) * 3072 + 1024 + h * 64 + seg * 8;
      *(uint4*)(Ks + row * KST + seg * 8)          = *(const uint4*)(qkv_v + g);
      *(uint4*)(Ks + PL + row * KST + seg * 8)     = *(const uint4*)(qkv_l + g);
      *(uint4*)(Ks + 2 * PL + row * KST + seg * 8) = *(const uint4*)(qkv_u + g);
    }
  }
  __syncthreads();
  for (int ct = 0; ct < 8; ct++) {
    const unsigned short* cur = (ct & 1) ? Vs : Ks;
    if (ct < 7) {
      unsigned short* nxt = (ct & 1) ? Ks : Vs;
      const int c0n = (ct + 1) * 64;
#pragma unroll
      for (int rep = 0; rep < 2; rep++) {
        const int unit = t + rep * 256, row = unit >> 3, seg = unit & 7;
        const size_t g = (size_t)(b * SEQ + c0n + row) * 3072 + 1024 + h * 64 + seg * 8;
        *(uint4*)(nxt + row * KST + seg * 8)          = *(const uint4*)(qkv_v + g);
        *(uint4*)(nxt + PL + row * KST + seg * 8)     = *(const uint4*)(qkv_l + g);
        *(uint4*)(nxt + 2 * PL + row * KST + seg * 8) = *(const uint4*)(qkv_u + g);
      }
    }
#pragma unroll
    for (int sub = 0; sub < 4; sub++) {
      const int cl = sub * 16 + r16;
      f32x4 av, al, au;
      qk_tile(cur, cur + PL, cur + 2 * PL, cl, quad,
              qvf, qlpf, qlnf, qupf, qunf, &av, &al, &au);
#pragma unroll
      for (int r = 0; r < 4; r++) {
        Svp[r] += __expf(av[r]);
        Slp[r] += __expf(al[r]);
        Sup[r] += __expf(au[r]);
      }
    }
    __syncthreads();
  }

  // finalize row sums (single reduction per row; lanes in quad-group share rows)
  float rSv4[4], Sl4[4], Su4[4];
#pragma unroll
  for (int r = 0; r < 4; r++) {
    rSv4[r] = 1.f / wave16_sum(Svp[r]);
    Sl4[r]  = wave16_sum(Slp[r]);
    Su4[r]  = wave16_sum(Sup[r]);
  }

  // ================= pass 2: P and P@V =================
  f32x4 oa[3][4];
#pragma unroll
  for (int bo = 0; bo < 3; bo++)
#pragma unroll
    for (int ds = 0; ds < 4; ds++) oa[bo][ds] = (f32x4){0.f, 0.f, 0.f, 0.f};

  for (int ct = 0; ct < 8; ct++) {
    const int c0 = ct * 64;
#pragma unroll
    for (int rep = 0; rep < 2; rep++) {
      const int unit = t + rep * 256, row = unit >> 3, seg = unit & 7;
      const size_t gk = (size_t)(b * SEQ + c0 + row) * 3072 + 1024 + h * 64 + seg * 8;
      *(uint4*)(Ks + row * KST + seg * 8)          = *(const uint4*)(qkv_v + gk);
      *(uint4*)(Ks + PL + row * KST + seg * 8)     = *(const uint4*)(qkv_l + gk);
      *(uint4*)(Ks + 2 * PL + row * KST + seg * 8) = *(const uint4*)(qkv_u + gk);
      const size_t gv = (size_t)(bh * 64 + row) * 512 + c0 + seg * 8;
      *(uint4*)(Vs + row * KST + seg * 8)          = *(const uint4*)(vt_v + gv);
      *(uint4*)(Vs + PL + row * KST + seg * 8)     = *(const uint4*)(vt_l + gv);
      *(uint4*)(Vs + 2 * PL + row * KST + seg * 8) = *(const uint4*)(vt_u + gv);
    }
    __syncthreads();

    // S -> p for this wave's stripe; write into own Ps rows (no barrier needed)
#pragma unroll
    for (int sub = 0; sub < 4; sub++) {
      const int cl = sub * 16 + r16;
      f32x4 av, al, au;
      qk_tile(Ks, Ks + PL, Ks + 2 * PL, cl, quad,
              qvf, qlpf, qlnf, qupf, qunf, &av, &al, &au);
#pragma unroll
      for (int r = 0; r < 4; r++) {
        const float ev = __expf(av[r]);
        const float el = __expf(al[r]);
        const float eu = __expf(au[r]);
        float pl = el * __builtin_amdgcn_rcpf(Su4[r] - eu + el);
        float pu = eu * __builtin_amdgcn_rcpf(Sl4[r] - el + eu);
        pl = fminf(fmaxf(pl, 0.f), 1.f);
        pu = fminf(fmaxf(pu, 0.f), 1.f);
        const int prow = (row0 + quad * 4 + r) * KST + cl;
        Ps[prow]          = f2b_fast(ev);   // unnormalized; 1/Sv folded at end
        Ps[PL + prow]     = f2b_fast(pl);
        Ps[2 * PL + prow] = f2b_fast(pu);
      }
    }

    // PV MFMAs (reads own Ps stripe + shared Vs)
#pragma unroll
    for (int dsub = 0; dsub < 4; dsub++) {
#pragma unroll
      for (int kseg = 0; kseg < 2; kseg++) {
        const int voff = (dsub * 16 + r16) * KST + kseg * 32 + quad * 8;
        bf16x8 vv = *(const bf16x8*)(Vs + voff);
        bf16x8 vl = *(const bf16x8*)(Vs + PL + voff);
        bf16x8 vu = *(const bf16x8*)(Vs + 2 * PL + voff);
        bf16x8 vlp, vln, vup, vun;
        clamp_pn8(vl, &vlp, &vln);
        clamp_pn8(vu, &vup, &vun);
        const int arow = (row0 + r16) * KST + kseg * 32 + quad * 8;
        bf16x8 pav = *(const bf16x8*)(Ps + arow);
        bf16x8 pal = *(const bf16x8*)(Ps + PL + arow);
        bf16x8 pau = *(const bf16x8*)(Ps + 2 * PL + arow);
        oa[0][dsub] = MFMA16(pav, vv, oa[0][dsub]);
        oa[1][dsub] = MFMA16(pal, vlp, oa[1][dsub]);
        oa[1][dsub] = MFMA16(pau, vln, oa[1][dsub]);
        oa[2][dsub] = MFMA16(pau, vup, oa[2][dsub]);
        oa[2][dsub] = MFMA16(pal, vun, oa[2][dsub]);
      }
    }
    __syncthreads();
  }

  // ---- epilogue: per-wave direct store (C-layout row=quad*4+r, col=r16) ----
#pragma unroll
  for (int dsub = 0; dsub < 4; dsub++) {
#pragma unroll
    for (int r = 0; r < 4; r++) {
      const size_t ro = (size_t)(mq + row0 + quad * 4 + r) * 1024 + h * 64 + dsub * 16 + r16;
      o_v[ro] = oa[0][dsub][r] * rSv4[r];
      o_l[ro] = oa[1][dsub][r];
      o_u[ro] = oa[2][dsub][r];
    }
  }
}

// ---------------------------------------------------------------------------
extern "C" void kernel_launch(void* const* d_in, const int* in_sizes, int n_in,
                              void* d_out, int out_size, void* d_ws, size_t ws_size,
                              hipStream_t stream)
{
  const float* x_val = (const float*)d_in[0];
  const float* x_lb  = (const float*)d_in[1];
  const float* x_ub  = (const float*)d_in[2];
  const float* Wi    = (const float*)d_in[3];
  const float* bi    = (const float*)d_in[4];
  const float* Wo    = (const float*)d_in[5];
  const float* bo    = (const float*)d_in[6];
  float* out = (float*)d_out;

  // ws layout (92.3 MB). Vt planes alias Xv/Xcr (dead during attention).
  char* p = (char*)d_ws;
  unsigned short* Xv  = (unsigned short*)p; p += (size_t)2048 * 1024 * 2;  // also Ov, Vt_v
  unsigned short* Xcr = (unsigned short*)p; p += (size_t)2048 * 2048 * 2;  // also Ocr, Vt_l/u
  unsigned short* Wit = (unsigned short*)p; p += (size_t)3072 * 1024 * 2;
  unsigned short* Wia = (unsigned short*)p; p += (size_t)3072 * 1024 * 2;
  unsigned short* Wot = (unsigned short*)p; p += (size_t)1024 * 1024 * 2;
  unsigned short* Woa = (unsigned short*)p; p += (size_t)1024 * 1024 * 2;
  unsigned short* qv  = (unsigned short*)p; p += (size_t)2048 * 3072 * 2;
  unsigned short* ql  = (unsigned short*)p; p += (size_t)2048 * 3072 * 2;
  unsigned short* qu  = (unsigned short*)p; p += (size_t)2048 * 3072 * 2;
  float* o_v = (float*)p; p += (size_t)2048 * 1024 * 4;
  float* o_l = (float*)p; p += (size_t)2048 * 1024 * 4;
  float* o_u = (float*)p; p += (size_t)2048 * 1024 * 4;

  unsigned short* Vtv = Xv;                               // [64][64][512] bf16
  unsigned short* Vtl = Xv + (size_t)64 * 64 * 512;
  unsigned short* Vtu = Xv + (size_t)2 * 64 * 64 * 512;

  // 1) convert inputs + weights to bf16
  convert_stack<<<2048, 256, 0, stream>>>(x_val, x_lb, x_ub, Xv, Xcr, 1024, 524288);
  wt_convert<<<dim3(96, 32), dim3(32, 8), 0, stream>>>(Wi, Wit, Wia, 1024, 3072);
  wt_convert<<<dim3(32, 32), dim3(32, 8), 0, stream>>>(Wo, Wot, Woa, 1024, 1024);

  // 2) in_proj GEMMs
  gemm_bt_bf16<<<dim3(24, 16), 256, 0, stream>>>(Xv, 1024, Wit, Wit, 1024, 0, bi, nullptr, qv, 3072);
  gemm_bt_bf16<<<dim3(24, 16), 256, 0, stream>>>(Xcr, 2048, Wit, Wia, 1024, 1, bi, nullptr, ql, 3072);
  gemm_bt_bf16<<<dim3(24, 16), 256, 0, stream>>>(Xcr, 2048, Wit, Wia, 1024, 0, bi, nullptr, qu, 3072);

  // 3) V transpose (Xv/Xcr now dead -> reuse as Vt)
  v_transpose<<<dim3(8, 64), 256, 0, stream>>>(qv, ql, qu, Vtv, Vtl, Vtu);

  // 4) MFMA IBP attention v2 (64 q-rows/block, independent waves)
  ibp_attn_mfma<<<dim3(SEQ / 64, NHEAD, NBAT), 256, 0, stream>>>(
      qv, ql, qu, Vtv, Vtl, Vtu, o_v, o_l, o_u);

  // 5) out_proj
  convert_stack<<<2048, 256, 0, stream>>>(o_v, o_l, o_u, Xv, Xcr, 1024, 524288);
  gemm_bt_bf16<<<dim3(8, 16), 256, 0, stream>>>(Xv, 1024, Wot, Wot, 1024, 0, bo,
                                                out, nullptr, 1024);
  gemm_bt_bf16<<<dim3(8, 16), 256, 0, stream>>>(Xcr, 2048, Wot, Woa, 1024, 1, bo,
                                                out + (size_t)2048 * 1024, nullptr, 1024);
  gemm_bt_bf16<<<dim3(8, 16), 256, 0, stream>>>(Xcr, 2048, Wot, Woa, 1024, 0, bo,
                                                out + (size_t)4096 * 1024, nullptr, 1024);
}

// Round 6
// 486.077 us; speedup vs baseline: 3.6213x; 1.4654x over previous
//
#include <hip/hip_runtime.h>
#include <math.h>

#define SEQ    512
#define EMB    1024
#define NHEAD  16
#define DHEAD  64
#define NBAT   4
#define QSCALE 0.125f   // 1/sqrt(64)
#define KS     72       // attn K-tile row stride (ushorts), 144B = 16B-mult, 2-way banks
#define VS     40       // attn V/P tile row stride (ushorts), 80B = 16B-mult, 2-way banks

typedef __attribute__((ext_vector_type(8))) short bf16x8;
typedef __attribute__((ext_vector_type(4))) float f32x4;

#define MFMA16(a, b, c) __builtin_amdgcn_mfma_f32_16x16x32_bf16(a, b, c, 0, 0, 0)

__device__ __forceinline__ unsigned short f2b(float x) {
  union { float f; unsigned int u; } a; a.f = x;
  unsigned int u = a.u;
  unsigned int r = (u + 0x7fffu + ((u >> 16) & 1u)) >> 16;   // RNE
  return (unsigned short)r;
}
__device__ __forceinline__ unsigned short f2b_fast(float x) {
  union { float f; unsigned int u; } a; a.f = x;
  return (unsigned short)((a.u + 0x8000u) >> 16);            // round-half-up, 2 ops
}
__device__ __forceinline__ float b2f(unsigned short x) {
  union { unsigned int u; float f; } a; a.u = ((unsigned int)x) << 16; return a.f;
}

// async global->LDS 16B: lds dst must be wave-uniform base (+ lane*16 by HW)
__device__ __forceinline__ void async16(const unsigned short* g, unsigned short* lds) {
  __builtin_amdgcn_global_load_lds(
      (const __attribute__((address_space(1))) unsigned int*)g,
      (__attribute__((address_space(3))) unsigned int*)lds, 16, 0, 0);
}

// packed sign-based split of bf16x8 into positive/negative parts (exact)
__device__ __forceinline__ void clamp_pn8(bf16x8 x, bf16x8* p, bf16x8* n) {
  const unsigned int* xu = (const unsigned int*)&x;
  unsigned int* pp = (unsigned int*)p;
  unsigned int* nn = (unsigned int*)n;
#pragma unroll
  for (int e = 0; e < 4; e++) {
    const unsigned int s = xu[e] & 0x80008000u;
    const unsigned int mask = s | (s - (s >> 15));   // 0xFFFF in negative halves
    nn[e] = xu[e] & mask;
    pp[e] = xu[e] & ~mask;
  }
}

__device__ __forceinline__ float wave16_sum(float x) {
#pragma unroll
  for (int m = 1; m <= 8; m <<= 1) x += __shfl_xor(x, m);
  return x;
}

// ---------------------------------------------------------------------------
// convert v,l,u fp32 -> bf16 planes: outV[m][k]=v, outCR[m][k]=c, outCR[m][K+k]=r
// ---------------------------------------------------------------------------
__global__ __launch_bounds__(256)
void convert_stack(const float* __restrict__ v, const float* __restrict__ l,
                   const float* __restrict__ u,
                   unsigned short* __restrict__ outV,
                   unsigned short* __restrict__ outCR,
                   int K, int total4)
{
  int i = blockIdx.x * 256 + threadIdx.x;
  if (i >= total4) return;
  float4 v4 = ((const float4*)v)[i];
  float4 l4 = ((const float4*)l)[i];
  float4 u4 = ((const float4*)u)[i];
  const int K4 = K >> 2;
  const int m = i / K4, k4 = i - m * K4;
  float lv[4] = {l4.x, l4.y, l4.z, l4.w};
  float uv[4] = {u4.x, u4.y, u4.z, u4.w};
  float vv[4] = {v4.x, v4.y, v4.z, v4.w};
  ushort4 ov, oc, orr;
  unsigned short* pv = (unsigned short*)&ov;
  unsigned short* pc = (unsigned short*)&oc;
  unsigned short* pr = (unsigned short*)&orr;
#pragma unroll
  for (int e = 0; e < 4; e++) {
    pv[e] = f2b(vv[e]);
    pc[e] = f2b(0.5f * (lv[e] + uv[e]));
    pr[e] = f2b(0.5f * (uv[e] - lv[e]));
  }
  ((ushort4*)outV)[i] = ov;
  ((ushort4*)outCR)[(size_t)m * (K4 * 2) + k4]      = oc;
  ((ushort4*)outCR)[(size_t)m * (K4 * 2) + K4 + k4] = orr;
}

// ---------------------------------------------------------------------------
// W [K][N] fp32 -> Wt [N][K] bf16 and Wabs_t [N][K] bf16 (tiled transpose)
// ---------------------------------------------------------------------------
__global__ __launch_bounds__(256)
void wt_convert(const float* __restrict__ W,
                unsigned short* __restrict__ Wt,
                unsigned short* __restrict__ Wa, int K, int N)
{
  __shared__ float tile[32][33];
  const int n0 = blockIdx.x * 32, k0 = blockIdx.y * 32;
  const int tx = threadIdx.x, ty = threadIdx.y;   // 32 x 8
#pragma unroll
  for (int r = 0; r < 32; r += 8)
    tile[ty + r][tx] = W[(size_t)(k0 + ty + r) * N + n0 + tx];
  __syncthreads();
#pragma unroll
  for (int r = 0; r < 32; r += 8) {
    const float w = tile[tx][ty + r];
    const size_t o = (size_t)(n0 + ty + r) * K + k0 + tx;
    Wt[o] = f2b(w);
    Wa[o] = f2b(fabsf(w));
  }
}

// ---------------------------------------------------------------------------
// bf16 GEMM, both operands k-major. 128x128 tile, BK=32, async global->LDS
// (width 16), unpadded [128][32] LDS tiles (m97 structure). B split at
// Ksplit with optional in-register negation of B2 fragments. Optional
// transposed V-plane side-output (n>=2048 region of the 3E in_proj).
// ---------------------------------------------------------------------------
__global__ __launch_bounds__(256)
void gemm_bt_bf16(const unsigned short* __restrict__ A, int Ktot,
                  const unsigned short* __restrict__ B1,
                  const unsigned short* __restrict__ B2,
                  int Ksplit, int negB2,
                  const float* __restrict__ bias,
                  float* __restrict__ outF, unsigned short* __restrict__ outH,
                  unsigned short* __restrict__ vtOut,
                  int N)
{
  __shared__ __attribute__((aligned(16))) unsigned short As[128 * 32];
  __shared__ __attribute__((aligned(16))) unsigned short Bs[128 * 32];

  const int t    = threadIdx.x;
  const int m0   = blockIdx.y * 128, n0 = blockIdx.x * 128;
  const int lane = t & 63, w = t >> 6;
  const int wm   = w >> 1, wn = w & 1;
  const int quad = lane >> 4, r16 = lane & 15;
  const int srow = lane >> 2, sseg = lane & 3;   // staging row/col within 16-row unit

  f32x4 acc[4][4];
#pragma unroll
  for (int i = 0; i < 4; i++)
#pragma unroll
    for (int j = 0; j < 4; j++)
      acc[i][j] = (f32x4){0.f, 0.f, 0.f, 0.f};

  for (int k0 = 0; k0 < Ktot; k0 += 32) {
    const unsigned short* Bb;
    int kb, bstride;
    if (k0 < Ksplit) { Bb = B1; kb = k0; bstride = Ksplit; }
    else             { Bb = B2; kb = k0 - Ksplit; bstride = Ktot - Ksplit; }
    const bool neg = (negB2 != 0) && (k0 >= Ksplit);

    __syncthreads();   // previous step's frag reads done before overwrite
    // async stage: wave w covers rows [w*32, w*32+32) of A and B tiles
#pragma unroll
    for (int r = 0; r < 2; r++) {
      const int row = w * 32 + r * 16 + srow;
      async16(A + (size_t)(m0 + row) * Ktot + k0 + sseg * 8,
              As + (w * 32 + r * 16) * 32);
      async16(Bb + (size_t)(n0 + row) * bstride + kb + sseg * 8,
              Bs + (w * 32 + r * 16) * 32);
    }
    __syncthreads();   // drain vmcnt + barrier

    bf16x8 af[4], bfr[4];
#pragma unroll
    for (int i = 0; i < 4; i++)
      af[i] = *(const bf16x8*)(As + (wm * 64 + i * 16 + r16) * 32 + quad * 8);
#pragma unroll
    for (int j = 0; j < 4; j++) {
      bfr[j] = *(const bf16x8*)(Bs + (wn * 64 + j * 16 + r16) * 32 + quad * 8);
      if (neg) {
        unsigned int* bu = (unsigned int*)&bfr[j];
#pragma unroll
        for (int e = 0; e < 4; e++) bu[e] ^= 0x80008000u;
      }
    }
#pragma unroll
    for (int i = 0; i < 4; i++)
#pragma unroll
      for (int j = 0; j < 4; j++)
        acc[i][j] = MFMA16(af[i], bfr[j], acc[i][j]);
  }

  // epilogue: C/D layout col=lane&15, row=quad*4+reg
#pragma unroll
  for (int i = 0; i < 4; i++) {
    const int mbase = m0 + wm * 64 + i * 16 + quad * 4;
#pragma unroll
    for (int j = 0; j < 4; j++) {
      const int n = n0 + wn * 64 + j * 16 + r16;
      const float bv = bias[n];
      float vals[4];
#pragma unroll
      for (int rI = 0; rI < 4; rI++) vals[rI] = acc[i][j][rI] + bv;
      if (outH) {
#pragma unroll
        for (int rI = 0; rI < 4; rI++) outH[(size_t)(mbase + rI) * N + n] = f2b(vals[rI]);
      } else {
#pragma unroll
        for (int rI = 0; rI < 4; rI++) outF[(size_t)(mbase + rI) * N + n] = vals[rI];
      }
      if (vtOut && n >= 2048) {
        const int hh = (n - 2048) >> 6, dd = (n - 2048) & 63;
        const int bb = mbase >> 9, ss = mbase & 511;
        ushort4 v4; unsigned short* vp = (unsigned short*)&v4;
#pragma unroll
        for (int rI = 0; rI < 4; rI++) vp[rI] = f2b(vals[rI]);
        *(ushort4*)(vtOut + (size_t)((bb * 16 + hh) * 64 + dd) * 512 + ss) = v4;
      }
    }
  }
}

// ---------------------------------------------------------------------------
// one 16x16 S sub-tile: 18 MFMA over K=64 (value 2, lb 8, ub 8)
// ---------------------------------------------------------------------------
__device__ __forceinline__ void qk_tile(const unsigned short* K0,
                                        const unsigned short* K1,
                                        const unsigned short* K2,
                                        int cl, int quad,
                                        const bf16x8 qvf[2], const bf16x8 qlpf[2],
                                        const bf16x8 qlnf[2], const bf16x8 qupf[2],
                                        const bf16x8 qunf[2],
                                        f32x4* avp, f32x4* alp, f32x4* aup)
{
  f32x4 v = {0.f, 0.f, 0.f, 0.f}, l = v, u = v;
#pragma unroll
  for (int kh = 0; kh < 2; kh++) {
    const int off = cl * KS + kh * 32 + quad * 8;
    bf16x8 kv = *(const bf16x8*)(K0 + off);
    bf16x8 kl = *(const bf16x8*)(K1 + off);
    bf16x8 ku = *(const bf16x8*)(K2 + off);
    bf16x8 klp, kln, kup, kun;
    clamp_pn8(kl, &klp, &kln);
    clamp_pn8(ku, &kup, &kun);
    v = MFMA16(qvf[kh], kv, v);
    l = MFMA16(qlpf[kh], klp, l);
    l = MFMA16(qupf[kh], kln, l);
    l = MFMA16(qlnf[kh], kup, l);
    l = MFMA16(qunf[kh], kun, l);
    u = MFMA16(qupf[kh], kup, u);
    u = MFMA16(qlpf[kh], kun, u);
    u = MFMA16(qunf[kh], klp, u);
    u = MFMA16(qlnf[kh], kln, u);
  }
  *avp = v; *alp = l; *aup = u;
}

// ---------------------------------------------------------------------------
// MFMA IBP attention v3: block = 32 q-rows x (b,h); 4 waves = 2 row-stripes
// (wm) x 2 splits (wc). s-tile = 32 cols. Pass 1: wave (wm,wc) computes cols
// wc*16+r16 of each tile -> raw exp sums, merged once via LDS. Pass 2: S,p
// for own cols -> Ps; barrier; PV d-split (wave covers d-half 32*wc), full
// k=32 per tile. Outputs written directly as bf16 Ov / Ocr planes.
// ---------------------------------------------------------------------------
__global__ __launch_bounds__(256, 4)
void ibp_attn_mfma(const unsigned short* __restrict__ qkv_v,
                   const unsigned short* __restrict__ qkv_l,
                   const unsigned short* __restrict__ qkv_u,
                   const unsigned short* __restrict__ vt_v,
                   const unsigned short* __restrict__ vt_l,
                   const unsigned short* __restrict__ vt_u,
                   unsigned short* __restrict__ Ov,
                   unsigned short* __restrict__ Ocr)
{
  // ushort pool: Ks 3x[32][KS]=6912, Vs 3x[64][VS]=7680, Ps 3x[32][VS]=3840
  __shared__ __attribute__((aligned(16))) unsigned short pool[6912 + 7680 + 3840];
  __shared__ float st[2][32][3];
  unsigned short* Ks = pool;                 // plane stride 2304
  unsigned short* Vs = pool + 6912;          // plane stride 2560
  unsigned short* Ps = pool + 6912 + 7680;   // plane stride 1280

  const int qblk = blockIdx.x, h = blockIdx.y, b = blockIdx.z;
  const int t = threadIdx.x, lane = t & 63, w = t >> 6;
  const int wm = w >> 1, wc = w & 1;
  const int quad = lane >> 4, r16 = lane & 15;
  const int mq = b * SEQ + qblk * 32;
  const int bh = b * NHEAD + h;

  // ---- Q fragments (A-layout: m=r16, k=quad*8+j), scaled + clamped ----
  bf16x8 qvf[2], qlpf[2], qlnf[2], qupf[2], qunf[2];
  {
    const size_t qrow = (size_t)(mq + wm * 16 + r16) * 3072 + h * 64;
#pragma unroll
    for (int kh = 0; kh < 2; kh++) {
      bf16x8 v8 = *(const bf16x8*)(qkv_v + qrow + kh * 32 + quad * 8);
      bf16x8 l8 = *(const bf16x8*)(qkv_l + qrow + kh * 32 + quad * 8);
      bf16x8 u8 = *(const bf16x8*)(qkv_u + qrow + kh * 32 + quad * 8);
      const unsigned short* vs = (const unsigned short*)&v8;
      const unsigned short* ls = (const unsigned short*)&l8;
      const unsigned short* us = (const unsigned short*)&u8;
      unsigned short* ov = (unsigned short*)&qvf[kh];
      unsigned short* lp = (unsigned short*)&qlpf[kh];
      unsigned short* ln = (unsigned short*)&qlnf[kh];
      unsigned short* up = (unsigned short*)&qupf[kh];
      unsigned short* un = (unsigned short*)&qunf[kh];
#pragma unroll
      for (int e = 0; e < 8; e++) {
        ov[e] = f2b(b2f(vs[e]) * QSCALE);
        const float lf = b2f(ls[e]) * QSCALE;
        const float uf = b2f(us[e]) * QSCALE;
        lp[e] = f2b(fmaxf(lf, 0.f)); ln[e] = f2b(fminf(lf, 0.f));
        up[e] = f2b(fmaxf(uf, 0.f)); un[e] = f2b(fminf(uf, 0.f));
      }
    }
  }

  const int cl = wc * 16 + r16;              // wave's column within a 32-s tile
  const int krow = t >> 3, kseg = t & 7;     // K staging: 32 rows x 8 segs
  const int vrow = t >> 2, vseg = t & 3;     // V staging: 64 rows x 4 segs
  const unsigned short* kplane[3] = {qkv_v, qkv_l, qkv_u};
  const unsigned short* vplane[3] = {vt_v, vt_l, vt_u};

  // ================= pass 1: raw exp row-sums (ping-pong K) =================
  float Svp[4] = {0.f, 0.f, 0.f, 0.f};
  float Slp[4] = {0.f, 0.f, 0.f, 0.f};
  float Sup[4] = {0.f, 0.f, 0.f, 0.f};

#pragma unroll
  for (int pI = 0; pI < 3; pI++)
    *(uint4*)(Ks + pI * 2304 + krow * KS + kseg * 8) =
        *(const uint4*)(kplane[pI] + (size_t)(b * SEQ + krow) * 3072 + 1024 + h * 64 + kseg * 8);
  __syncthreads();

  for (int ct = 0; ct < 16; ct++) {
    const unsigned short* cur = (ct & 1) ? Vs : Ks;
    if (ct < 15) {
      unsigned short* nxt = (ct & 1) ? Ks : Vs;
      const int c0n = (ct + 1) * 32;
#pragma unroll
      for (int pI = 0; pI < 3; pI++)
        *(uint4*)(nxt + pI * 2304 + krow * KS + kseg * 8) =
            *(const uint4*)(kplane[pI] + (size_t)(b * SEQ + c0n + krow) * 3072 + 1024 + h * 64 + kseg * 8);
    }
    f32x4 av, al, au;
    qk_tile(cur, cur + 2304, cur + 4608, cl, quad,
            qvf, qlpf, qlnf, qupf, qunf, &av, &al, &au);
#pragma unroll
    for (int r = 0; r < 4; r++) {
      Svp[r] += __expf(av[r]);
      Slp[r] += __expf(al[r]);
      Sup[r] += __expf(au[r]);
    }
    __syncthreads();
  }

  // merge sums: reduce within wave (over r16), then across the 2 col-halves
#pragma unroll
  for (int r = 0; r < 4; r++) {
    Svp[r] = wave16_sum(Svp[r]);
    Slp[r] = wave16_sum(Slp[r]);
    Sup[r] = wave16_sum(Sup[r]);
  }
  if (r16 == 0) {
#pragma unroll
    for (int r = 0; r < 4; r++) {
      st[wc][wm * 16 + quad * 4 + r][0] = Svp[r];
      st[wc][wm * 16 + quad * 4 + r][1] = Slp[r];
      st[wc][wm * 16 + quad * 4 + r][2] = Sup[r];
    }
  }
  __syncthreads();
  float rSv4[4], Sl4[4], Su4[4];
#pragma unroll
  for (int r = 0; r < 4; r++) {
    const int row = wm * 16 + quad * 4 + r;
    rSv4[r] = 1.f / (st[0][row][0] + st[1][row][0]);
    Sl4[r]  = st[0][row][1] + st[1][row][1];
    Su4[r]  = st[0][row][2] + st[1][row][2];
  }

  // ================= pass 2: p and P@V (d-split PV) =================
  f32x4 oa[3][2];
#pragma unroll
  for (int bo = 0; bo < 3; bo++)
#pragma unroll
    for (int ds = 0; ds < 2; ds++) oa[bo][ds] = (f32x4){0.f, 0.f, 0.f, 0.f};

  for (int ct = 0; ct < 16; ct++) {
    const int c0 = ct * 32;
    __syncthreads();   // prior PV reads done before restage
#pragma unroll
    for (int pI = 0; pI < 3; pI++) {
      *(uint4*)(Ks + pI * 2304 + krow * KS + kseg * 8) =
          *(const uint4*)(kplane[pI] + (size_t)(b * SEQ + c0 + krow) * 3072 + 1024 + h * 64 + kseg * 8);
      *(uint4*)(Vs + pI * 2560 + vrow * VS + vseg * 8) =
          *(const uint4*)(vplane[pI] + (size_t)(bh * 64 + vrow) * 512 + c0 + vseg * 8);
    }
    __syncthreads();

    f32x4 av, al, au;
    qk_tile(Ks, Ks + 2304, Ks + 4608, cl, quad,
            qvf, qlpf, qlnf, qupf, qunf, &av, &al, &au);
#pragma unroll
    for (int r = 0; r < 4; r++) {
      const float ev = __expf(av[r]);
      const float el = __expf(al[r]);
      const float eu = __expf(au[r]);
      float pl = el * __builtin_amdgcn_rcpf(Su4[r] - eu + el);
      float pu = eu * __builtin_amdgcn_rcpf(Sl4[r] - el + eu);
      pl = fminf(fmaxf(pl, 0.f), 1.f);
      pu = fminf(fmaxf(pu, 0.f), 1.f);
      const int prow = (wm * 16 + quad * 4 + r) * VS + cl;
      Ps[prow]        = f2b_fast(ev);   // unnormalized; 1/Sv folded in epilogue
      Ps[1280 + prow] = f2b_fast(pl);
      Ps[2560 + prow] = f2b_fast(pu);
    }
    __syncthreads();   // Ps complete across both col-halves

    // PV: wave covers d-half wc (dsub = 2*wc + ds), full k=32 of this tile
#pragma unroll
    for (int ds = 0; ds < 2; ds++) {
      const int dsub = wc * 2 + ds;
      const int voff = (dsub * 16 + r16) * VS + quad * 8;
      bf16x8 vv = *(const bf16x8*)(Vs + voff);
      bf16x8 vl = *(const bf16x8*)(Vs + 2560 + voff);
      bf16x8 vu = *(const bf16x8*)(Vs + 5120 + voff);
      bf16x8 vlp, vln, vup, vun;
      clamp_pn8(vl, &vlp, &vln);
      clamp_pn8(vu, &vup, &vun);
      const int arow = (wm * 16 + r16) * VS + quad * 8;
      bf16x8 pav = *(const bf16x8*)(Ps + arow);
      bf16x8 pal = *(const bf16x8*)(Ps + 1280 + arow);
      bf16x8 pau = *(const bf16x8*)(Ps + 2560 + arow);
      oa[0][ds] = MFMA16(pav, vv, oa[0][ds]);
      oa[1][ds] = MFMA16(pal, vlp, oa[1][ds]);
      oa[1][ds] = MFMA16(pau, vln, oa[1][ds]);
      oa[2][ds] = MFMA16(pau, vup, oa[2][ds]);
      oa[2][ds] = MFMA16(pal, vun, oa[2][ds]);
    }
  }

  // ---- epilogue: direct bf16 stores into Ov [2048][1024] / Ocr [2048][2048]
#pragma unroll
  for (int ds = 0; ds < 2; ds++) {
    const int dsub = wc * 2 + ds;
#pragma unroll
    for (int r = 0; r < 4; r++) {
      const size_t row = (size_t)(mq + wm * 16 + quad * 4 + r);
      const int col = h * 64 + dsub * 16 + r16;
      const float ovv = oa[0][ds][r] * rSv4[r];
      const float olv = oa[1][ds][r];
      const float ouv = oa[2][ds][r];
      Ov[row * 1024 + col]         = f2b(ovv);
      Ocr[row * 2048 + col]        = f2b(0.5f * (olv + ouv));
      Ocr[row * 2048 + 1024 + col] = f2b(0.5f * (ouv - olv));
    }
  }
}

// ---------------------------------------------------------------------------
extern "C" void kernel_launch(void* const* d_in, const int* in_sizes, int n_in,
                              void* d_out, int out_size, void* d_ws, size_t ws_size,
                              hipStream_t stream)
{
  const float* x_val = (const float*)d_in[0];
  const float* x_lb  = (const float*)d_in[1];
  const float* x_ub  = (const float*)d_in[2];
  const float* Wi    = (const float*)d_in[3];
  const float* bi    = (const float*)d_in[4];
  const float* Wo    = (const float*)d_in[5];
  const float* bo    = (const float*)d_in[6];
  float* out = (float*)d_out;

  // ws layout (~78.3 MB). Xv/Xcr are reused as attn outputs Ov/Ocr (bf16).
  char* p = (char*)d_ws;
  unsigned short* Xv  = (unsigned short*)p; p += (size_t)2048 * 1024 * 2;  // then Ov
  unsigned short* Xcr = (unsigned short*)p; p += (size_t)2048 * 2048 * 2;  // then Ocr
  unsigned short* Wit = (unsigned short*)p; p += (size_t)3072 * 1024 * 2;
  unsigned short* Wia = (unsigned short*)p; p += (size_t)3072 * 1024 * 2;
  unsigned short* Wot = (unsigned short*)p; p += (size_t)1024 * 1024 * 2;
  unsigned short* Woa = (unsigned short*)p; p += (size_t)1024 * 1024 * 2;
  unsigned short* qv  = (unsigned short*)p; p += (size_t)2048 * 3072 * 2;
  unsigned short* ql  = (unsigned short*)p; p += (size_t)2048 * 3072 * 2;
  unsigned short* qu  = (unsigned short*)p; p += (size_t)2048 * 3072 * 2;
  unsigned short* Vtv = (unsigned short*)p; p += (size_t)64 * 64 * 512 * 2;
  unsigned short* Vtl = (unsigned short*)p; p += (size_t)64 * 64 * 512 * 2;
  unsigned short* Vtu = (unsigned short*)p; p += (size_t)64 * 64 * 512 * 2;

  // 1) convert inputs + weights to bf16
  convert_stack<<<2048, 256, 0, stream>>>(x_val, x_lb, x_ub, Xv, Xcr, 1024, 524288);
  wt_convert<<<dim3(96, 32), dim3(32, 8), 0, stream>>>(Wi, Wit, Wia, 1024, 3072);
  wt_convert<<<dim3(32, 32), dim3(32, 8), 0, stream>>>(Wo, Wot, Woa, 1024, 1024);

  // 2) in_proj GEMMs (emit qkv planes + transposed V side-output)
  gemm_bt_bf16<<<dim3(24, 16), 256, 0, stream>>>(Xv, 1024, Wit, Wit, 1024, 0, bi,
                                                 nullptr, qv, Vtv, 3072);
  gemm_bt_bf16<<<dim3(24, 16), 256, 0, stream>>>(Xcr, 2048, Wit, Wia, 1024, 1, bi,
                                                 nullptr, ql, Vtl, 3072);
  gemm_bt_bf16<<<dim3(24, 16), 256, 0, stream>>>(Xcr, 2048, Wit, Wia, 1024, 0, bi,
                                                 nullptr, qu, Vtu, 3072);

  // 3) MFMA IBP attention v3 -> writes Ov/Ocr bf16 directly into Xv/Xcr
  ibp_attn_mfma<<<dim3(SEQ / 32, NHEAD, NBAT), 256, 0, stream>>>(
      qv, ql, qu, Vtv, Vtl, Vtu, Xv, Xcr);

  // 4) out_proj GEMMs -> [3,B,S,E] fp32
  gemm_bt_bf16<<<dim3(8, 16), 256, 0, stream>>>(Xv, 1024, Wot, Wot, 1024, 0, bo,
                                                out, nullptr, nullptr, 1024);
  gemm_bt_bf16<<<dim3(8, 16), 256, 0, stream>>>(Xcr, 2048, Wot, Woa, 1024, 1, bo,
                                                out + (size_t)2048 * 1024, nullptr, nullptr, 1024);
  gemm_bt_bf16<<<dim3(8, 16), 256, 0, stream>>>(Xcr, 2048, Wot, Woa, 1024, 0, bo,
                                                out + (size_t)4096 * 1024, nullptr, nullptr, 1024);
}

// Round 7
// 319.991 us; speedup vs baseline: 5.5009x; 1.5190x over previous
//
#include <hip/hip_runtime.h>
#include <math.h>

#define SEQ    512
#define EMB    1024
#define NHEAD  16
#define DHEAD  64
#define NBAT   4
#define QSCALE 0.125f   // 1/sqrt(64)
#define KS     72       // attn K-tile row stride (ushorts)
#define VS     40       // attn V/P tile row stride (ushorts)

typedef __attribute__((ext_vector_type(8))) short bf16x8;
typedef __attribute__((ext_vector_type(4))) float f32x4;

#define MFMA16(a, b, c) __builtin_amdgcn_mfma_f32_16x16x32_bf16(a, b, c, 0, 0, 0)

__device__ __forceinline__ unsigned short f2b(float x) {
  union { float f; unsigned int u; } a; a.f = x;
  unsigned int u = a.u;
  unsigned int r = (u + 0x7fffu + ((u >> 16) & 1u)) >> 16;   // RNE
  return (unsigned short)r;
}
__device__ __forceinline__ unsigned short f2b_fast(float x) {
  union { float f; unsigned int u; } a; a.f = x;
  return (unsigned short)((a.u + 0x8000u) >> 16);            // round-half-up
}
__device__ __forceinline__ float b2f(unsigned short x) {
  union { unsigned int u; float f; } a; a.u = ((unsigned int)x) << 16; return a.f;
}

// async global->LDS 16B: lds dst is wave-uniform base (+ lane*16 by HW)
__device__ __forceinline__ void async16(const unsigned short* g, unsigned short* lds) {
  __builtin_amdgcn_global_load_lds(
      (const __attribute__((address_space(1))) unsigned int*)g,
      (__attribute__((address_space(3))) unsigned int*)lds, 16, 0, 0);
}

// packed sign-based split of bf16x8 into positive/negative parts (exact)
__device__ __forceinline__ void clamp_pn8(bf16x8 x, bf16x8* p, bf16x8* n) {
  const unsigned int* xu = (const unsigned int*)&x;
  unsigned int* pp = (unsigned int*)p;
  unsigned int* nn = (unsigned int*)n;
#pragma unroll
  for (int e = 0; e < 4; e++) {
    const unsigned int s = xu[e] & 0x80008000u;
    const unsigned int mask = s | (s - (s >> 15));   // 0xFFFF in negative halves
    nn[e] = xu[e] & mask;
    pp[e] = xu[e] & ~mask;
  }
}

__device__ __forceinline__ float wave16_sum(float x) {
#pragma unroll
  for (int m = 1; m <= 8; m <<= 1) x += __shfl_xor(x, m);
  return x;
}

// ---------------------------------------------------------------------------
// convert v,l,u fp32 -> bf16 planes Xv, Xc, Xr (all [M][1024])
// ---------------------------------------------------------------------------
__global__ __launch_bounds__(256)
void convert_stack(const float* __restrict__ v, const float* __restrict__ l,
                   const float* __restrict__ u,
                   unsigned short* __restrict__ outV,
                   unsigned short* __restrict__ outC,
                   unsigned short* __restrict__ outR, int total4)
{
  int i = blockIdx.x * 256 + threadIdx.x;
  if (i >= total4) return;
  float4 v4 = ((const float4*)v)[i];
  float4 l4 = ((const float4*)l)[i];
  float4 u4 = ((const float4*)u)[i];
  float lv[4] = {l4.x, l4.y, l4.z, l4.w};
  float uv[4] = {u4.x, u4.y, u4.z, u4.w};
  float vv[4] = {v4.x, v4.y, v4.z, v4.w};
  ushort4 ov, oc, orr;
  unsigned short* pv = (unsigned short*)&ov;
  unsigned short* pc = (unsigned short*)&oc;
  unsigned short* pr = (unsigned short*)&orr;
#pragma unroll
  for (int e = 0; e < 4; e++) {
    pv[e] = f2b(vv[e]);
    pc[e] = f2b(0.5f * (lv[e] + uv[e]));
    pr[e] = f2b(0.5f * (uv[e] - lv[e]));
  }
  ((ushort4*)outV)[i] = ov;
  ((ushort4*)outC)[i] = oc;
  ((ushort4*)outR)[i] = orr;
}

// ---------------------------------------------------------------------------
// W [K][N] fp32 -> Wt [N][K] bf16 and Wabs_t [N][K] bf16 (tiled transpose)
// ---------------------------------------------------------------------------
__global__ __launch_bounds__(256)
void wt_convert(const float* __restrict__ W,
                unsigned short* __restrict__ Wt,
                unsigned short* __restrict__ Wa, int K, int N)
{
  __shared__ float tile[32][33];
  const int n0 = blockIdx.x * 32, k0 = blockIdx.y * 32;
  const int tx = threadIdx.x, ty = threadIdx.y;   // 32 x 8
#pragma unroll
  for (int r = 0; r < 32; r += 8)
    tile[ty + r][tx] = W[(size_t)(k0 + ty + r) * N + n0 + tx];
  __syncthreads();
#pragma unroll
  for (int r = 0; r < 32; r += 8) {
    const float w = tile[tx][ty + r];
    const size_t o = (size_t)(n0 + ty + r) * K + k0 + tx;
    Wt[o] = f2b(w);
    Wa[o] = f2b(fabsf(w));
  }
}

// ---------------------------------------------------------------------------
// Plain bf16 GEMM, k-major both sides. BM=64, BN=128, BK=32, 256 threads,
// double-buffered async global->LDS, ONE barrier per k-iter:
//   barrier -> issue stage(next) -> MFMA(cur)   (loads fly during compute)
// Optional transposed V side-output for n>=2048.
// ---------------------------------------------------------------------------
__global__ __launch_bounds__(256)
void gemm_v_bf16(const unsigned short* __restrict__ A,
                 const unsigned short* __restrict__ B,
                 int K, const float* __restrict__ bias,
                 float* __restrict__ outF, unsigned short* __restrict__ outH,
                 unsigned short* __restrict__ vtOut, int N)
{
  __shared__ __attribute__((aligned(16))) unsigned short As[2][64 * 32];
  __shared__ __attribute__((aligned(16))) unsigned short Bs[2][128 * 32];

  const int t = threadIdx.x, lane = t & 63, w = t >> 6;
  const int m0 = blockIdx.y * 64, n0 = blockIdx.x * 128;
  const int wm = w & 1, wn = w >> 1;
  const int quad = lane >> 4, r16 = lane & 15;
  const int srow = lane >> 2, sseg = lane & 3;

  f32x4 acc[2][4];
#pragma unroll
  for (int i = 0; i < 2; i++)
#pragma unroll
    for (int j = 0; j < 4; j++) acc[i][j] = (f32x4){0.f, 0.f, 0.f, 0.f};

  const int iters = K >> 5;
  auto stage = [&](int it, int buf) {
    const int k0 = it * 32;
    async16(A + (size_t)(m0 + 16 * w + srow) * K + k0 + sseg * 8,
            &As[buf][16 * w * 32]);
#pragma unroll
    for (int r = 0; r < 2; r++)
      async16(B + (size_t)(n0 + 32 * w + 16 * r + srow) * K + k0 + sseg * 8,
              &Bs[buf][(32 * w + 16 * r) * 32]);
  };

  stage(0, 0);
  for (int it = 0; it < iters; ++it) {
    const int cur = it & 1;
    __syncthreads();                       // drains cur's loads (all waves)
    if (it + 1 < iters) stage(it + 1, cur ^ 1);
    bf16x8 af[2], bfr[4];
#pragma unroll
    for (int i = 0; i < 2; i++)
      af[i] = *(const bf16x8*)(&As[cur][(wm * 32 + i * 16 + r16) * 32 + quad * 8]);
#pragma unroll
    for (int j = 0; j < 4; j++)
      bfr[j] = *(const bf16x8*)(&Bs[cur][(wn * 64 + j * 16 + r16) * 32 + quad * 8]);
#pragma unroll
    for (int i = 0; i < 2; i++)
#pragma unroll
      for (int j = 0; j < 4; j++)
        acc[i][j] = MFMA16(af[i], bfr[j], acc[i][j]);
  }

#pragma unroll
  for (int i = 0; i < 2; i++) {
    const int mbase = m0 + wm * 32 + i * 16 + quad * 4;
#pragma unroll
    for (int j = 0; j < 4; j++) {
      const int n = n0 + wn * 64 + j * 16 + r16;
      const float bv = bias[n];
      float vals[4];
#pragma unroll
      for (int rI = 0; rI < 4; rI++) vals[rI] = acc[i][j][rI] + bv;
      if (outH) {
#pragma unroll
        for (int rI = 0; rI < 4; rI++) outH[(size_t)(mbase + rI) * N + n] = f2b(vals[rI]);
      } else {
#pragma unroll
        for (int rI = 0; rI < 4; rI++) outF[(size_t)(mbase + rI) * N + n] = vals[rI];
      }
      if (vtOut && n >= 2048) {
        const int hh = (n - 2048) >> 6, dd = (n - 2048) & 63;
        const int bb = mbase >> 9, ss = mbase & 511;
        ushort4 v4; unsigned short* vp = (unsigned short*)&v4;
#pragma unroll
        for (int rI = 0; rI < 4; rI++) vp[rI] = f2b(vals[rI]);
        *(ushort4*)(vtOut + (size_t)((bb * 16 + hh) * 64 + dd) * 512 + ss) = v4;
      }
    }
  }
}

// ---------------------------------------------------------------------------
// Fused center/radius interval GEMM: acc_c = Ac@Bt, acc_r = Ar@Ba, then
// l = c - r + bias, u = c + r + bias. Same tile/pipeline as gemm_v.
// ---------------------------------------------------------------------------
__global__ __launch_bounds__(256)
void gemm_cr_bf16(const unsigned short* __restrict__ Ac,
                  const unsigned short* __restrict__ Ar,
                  const unsigned short* __restrict__ Bt,
                  const unsigned short* __restrict__ Ba,
                  int K, const float* __restrict__ bias,
                  float* __restrict__ outFl, float* __restrict__ outFu,
                  unsigned short* __restrict__ outHl, unsigned short* __restrict__ outHu,
                  unsigned short* __restrict__ vtL, unsigned short* __restrict__ vtU,
                  int N)
{
  __shared__ __attribute__((aligned(16))) unsigned short Acs[2][64 * 32];
  __shared__ __attribute__((aligned(16))) unsigned short Ars[2][64 * 32];
  __shared__ __attribute__((aligned(16))) unsigned short Bts[2][128 * 32];
  __shared__ __attribute__((aligned(16))) unsigned short Bas[2][128 * 32];

  const int t = threadIdx.x, lane = t & 63, w = t >> 6;
  const int m0 = blockIdx.y * 64, n0 = blockIdx.x * 128;
  const int wm = w & 1, wn = w >> 1;
  const int quad = lane >> 4, r16 = lane & 15;
  const int srow = lane >> 2, sseg = lane & 3;

  f32x4 ac_[2][4], arr[2][4];
#pragma unroll
  for (int i = 0; i < 2; i++)
#pragma unroll
    for (int j = 0; j < 4; j++) {
      ac_[i][j] = (f32x4){0.f, 0.f, 0.f, 0.f};
      arr[i][j] = (f32x4){0.f, 0.f, 0.f, 0.f};
    }

  const int iters = K >> 5;
  auto stage = [&](int it, int buf) {
    const int k0 = it * 32;
    const size_t ga = (size_t)(m0 + 16 * w + srow) * K + k0 + sseg * 8;
    async16(Ac + ga, &Acs[buf][16 * w * 32]);
    async16(Ar + ga, &Ars[buf][16 * w * 32]);
#pragma unroll
    for (int r = 0; r < 2; r++) {
      const size_t gb = (size_t)(n0 + 32 * w + 16 * r + srow) * K + k0 + sseg * 8;
      async16(Bt + gb, &Bts[buf][(32 * w + 16 * r) * 32]);
      async16(Ba + gb, &Bas[buf][(32 * w + 16 * r) * 32]);
    }
  };

  stage(0, 0);
  for (int it = 0; it < iters; ++it) {
    const int cur = it & 1;
    __syncthreads();
    if (it + 1 < iters) stage(it + 1, cur ^ 1);
    bf16x8 afc[2], afr[2], bft[4], bfa[4];
#pragma unroll
    for (int i = 0; i < 2; i++) {
      const int off = (wm * 32 + i * 16 + r16) * 32 + quad * 8;
      afc[i] = *(const bf16x8*)(&Acs[cur][off]);
      afr[i] = *(const bf16x8*)(&Ars[cur][off]);
    }
#pragma unroll
    for (int j = 0; j < 4; j++) {
      const int off = (wn * 64 + j * 16 + r16) * 32 + quad * 8;
      bft[j] = *(const bf16x8*)(&Bts[cur][off]);
      bfa[j] = *(const bf16x8*)(&Bas[cur][off]);
    }
#pragma unroll
    for (int i = 0; i < 2; i++)
#pragma unroll
      for (int j = 0; j < 4; j++) {
        ac_[i][j] = MFMA16(afc[i], bft[j], ac_[i][j]);
        arr[i][j] = MFMA16(afr[i], bfa[j], arr[i][j]);
      }
  }

#pragma unroll
  for (int i = 0; i < 2; i++) {
    const int mbase = m0 + wm * 32 + i * 16 + quad * 4;
#pragma unroll
    for (int j = 0; j < 4; j++) {
      const int n = n0 + wn * 64 + j * 16 + r16;
      const float bv = bias[n];
      float lv[4], uv[4];
#pragma unroll
      for (int rI = 0; rI < 4; rI++) {
        const float c = ac_[i][j][rI], r = arr[i][j][rI];
        lv[rI] = c - r + bv;
        uv[rI] = c + r + bv;
      }
      if (outHl) {
#pragma unroll
        for (int rI = 0; rI < 4; rI++) {
          outHl[(size_t)(mbase + rI) * N + n] = f2b(lv[rI]);
          outHu[(size_t)(mbase + rI) * N + n] = f2b(uv[rI]);
        }
      } else {
#pragma unroll
        for (int rI = 0; rI < 4; rI++) {
          outFl[(size_t)(mbase + rI) * N + n] = lv[rI];
          outFu[(size_t)(mbase + rI) * N + n] = uv[rI];
        }
      }
      if (vtL && n >= 2048) {
        const int hh = (n - 2048) >> 6, dd = (n - 2048) & 63;
        const int bb = mbase >> 9, ss = mbase & 511;
        ushort4 l4, u4;
        unsigned short* lp = (unsigned short*)&l4;
        unsigned short* up = (unsigned short*)&u4;
#pragma unroll
        for (int rI = 0; rI < 4; rI++) { lp[rI] = f2b(lv[rI]); up[rI] = f2b(uv[rI]); }
        const size_t vo = (size_t)((bb * 16 + hh) * 64 + dd) * 512 + ss;
        *(ushort4*)(vtL + vo) = l4;
        *(ushort4*)(vtU + vo) = u4;
      }
    }
  }
}

// ---------------------------------------------------------------------------
// one 16x16 S sub-tile: 18 MFMA over K=64 (value 2, lb 8, ub 8)
// ---------------------------------------------------------------------------
__device__ __forceinline__ void qk_tile(const unsigned short* K0,
                                        const unsigned short* K1,
                                        const unsigned short* K2,
                                        int cl, int quad,
                                        const bf16x8 qvf[2], const bf16x8 qlpf[2],
                                        const bf16x8 qlnf[2], const bf16x8 qupf[2],
                                        const bf16x8 qunf[2],
                                        f32x4* avp, f32x4* alp, f32x4* aup)
{
  f32x4 v = {0.f, 0.f, 0.f, 0.f}, l = v, u = v;
#pragma unroll
  for (int kh = 0; kh < 2; kh++) {
    const int off = cl * KS + kh * 32 + quad * 8;
    bf16x8 kv = *(const bf16x8*)(K0 + off);
    bf16x8 kl = *(const bf16x8*)(K1 + off);
    bf16x8 ku = *(const bf16x8*)(K2 + off);
    bf16x8 klp, kln, kup, kun;
    clamp_pn8(kl, &klp, &kln);
    clamp_pn8(ku, &kup, &kun);
    v = MFMA16(qvf[kh], kv, v);
    l = MFMA16(qlpf[kh], klp, l);
    l = MFMA16(qupf[kh], kln, l);
    l = MFMA16(qlnf[kh], kup, l);
    l = MFMA16(qunf[kh], kun, l);
    u = MFMA16(qupf[kh], kup, u);
    u = MFMA16(qlpf[kh], kun, u);
    u = MFMA16(qunf[kh], klp, u);
    u = MFMA16(qlnf[kh], kln, u);
  }
  *avp = v; *alp = l; *aup = u;
}

// ---------------------------------------------------------------------------
// MFMA IBP attention v3 (unchanged structure from R6); outputs split planes
// Ov / Oc / Or (bf16, [2048][1024]) feeding gemm_v / gemm_cr directly.
// ---------------------------------------------------------------------------
__global__ __launch_bounds__(256, 4)
void ibp_attn_mfma(const unsigned short* __restrict__ qkv_v,
                   const unsigned short* __restrict__ qkv_l,
                   const unsigned short* __restrict__ qkv_u,
                   const unsigned short* __restrict__ vt_v,
                   const unsigned short* __restrict__ vt_l,
                   const unsigned short* __restrict__ vt_u,
                   unsigned short* __restrict__ Ov,
                   unsigned short* __restrict__ Oc,
                   unsigned short* __restrict__ Or)
{
  __shared__ __attribute__((aligned(16))) unsigned short pool[6912 + 7680 + 3840];
  __shared__ float st[2][32][3];
  unsigned short* Ks = pool;                 // 3 planes, stride 2304
  unsigned short* Vs = pool + 6912;          // 3 planes, stride 2560
  unsigned short* Ps = pool + 6912 + 7680;   // 3 planes, stride 1280

  const int qblk = blockIdx.x, h = blockIdx.y, b = blockIdx.z;
  const int t = threadIdx.x, lane = t & 63, w = t >> 6;
  const int wm = w >> 1, wc = w & 1;
  const int quad = lane >> 4, r16 = lane & 15;
  const int mq = b * SEQ + qblk * 32;
  const int bh = b * NHEAD + h;

  bf16x8 qvf[2], qlpf[2], qlnf[2], qupf[2], qunf[2];
  {
    const size_t qrow = (size_t)(mq + wm * 16 + r16) * 3072 + h * 64;
#pragma unroll
    for (int kh = 0; kh < 2; kh++) {
      bf16x8 v8 = *(const bf16x8*)(qkv_v + qrow + kh * 32 + quad * 8);
      bf16x8 l8 = *(const bf16x8*)(qkv_l + qrow + kh * 32 + quad * 8);
      bf16x8 u8 = *(const bf16x8*)(qkv_u + qrow + kh * 32 + quad * 8);
      const unsigned short* vs = (const unsigned short*)&v8;
      const unsigned short* ls = (const unsigned short*)&l8;
      const unsigned short* us = (const unsigned short*)&u8;
      unsigned short* ov = (unsigned short*)&qvf[kh];
      unsigned short* lp = (unsigned short*)&qlpf[kh];
      unsigned short* ln = (unsigned short*)&qlnf[kh];
      unsigned short* up = (unsigned short*)&qupf[kh];
      unsigned short* un = (unsigned short*)&qunf[kh];
#pragma unroll
      for (int e = 0; e < 8; e++) {
        ov[e] = f2b(b2f(vs[e]) * QSCALE);
        const float lf = b2f(ls[e]) * QSCALE;
        const float uf = b2f(us[e]) * QSCALE;
        lp[e] = f2b(fmaxf(lf, 0.f)); ln[e] = f2b(fminf(lf, 0.f));
        up[e] = f2b(fmaxf(uf, 0.f)); un[e] = f2b(fminf(uf, 0.f));
      }
    }
  }

  const int cl = wc * 16 + r16;
  const int krow = t >> 3, kseg = t & 7;
  const int vrow = t >> 2, vseg = t & 3;
  const unsigned short* kplane[3] = {qkv_v, qkv_l, qkv_u};
  const unsigned short* vplane[3] = {vt_v, vt_l, vt_u};

  // ---- pass 1: raw exp row-sums (ping-pong K) ----
  float Svp[4] = {0.f, 0.f, 0.f, 0.f};
  float Slp[4] = {0.f, 0.f, 0.f, 0.f};
  float Sup[4] = {0.f, 0.f, 0.f, 0.f};

#pragma unroll
  for (int pI = 0; pI < 3; pI++)
    *(uint4*)(Ks + pI * 2304 + krow * KS + kseg * 8) =
        *(const uint4*)(kplane[pI] + (size_t)(b * SEQ + krow) * 3072 + 1024 + h * 64 + kseg * 8);
  __syncthreads();

  for (int ct = 0; ct < 16; ct++) {
    const unsigned short* cur = (ct & 1) ? Vs : Ks;
    if (ct < 15) {
      unsigned short* nxt = (ct & 1) ? Ks : Vs;
      const int c0n = (ct + 1) * 32;
#pragma unroll
      for (int pI = 0; pI < 3; pI++)
        *(uint4*)(nxt + pI * 2304 + krow * KS + kseg * 8) =
            *(const uint4*)(kplane[pI] + (size_t)(b * SEQ + c0n + krow) * 3072 + 1024 + h * 64 + kseg * 8);
    }
    f32x4 av, al, au;
    qk_tile(cur, cur + 2304, cur + 4608, cl, quad,
            qvf, qlpf, qlnf, qupf, qunf, &av, &al, &au);
#pragma unroll
    for (int r = 0; r < 4; r++) {
      Svp[r] += __expf(av[r]);
      Slp[r] += __expf(al[r]);
      Sup[r] += __expf(au[r]);
    }
    __syncthreads();
  }

#pragma unroll
  for (int r = 0; r < 4; r++) {
    Svp[r] = wave16_sum(Svp[r]);
    Slp[r] = wave16_sum(Slp[r]);
    Sup[r] = wave16_sum(Sup[r]);
  }
  if (r16 == 0) {
#pragma unroll
    for (int r = 0; r < 4; r++) {
      st[wc][wm * 16 + quad * 4 + r][0] = Svp[r];
      st[wc][wm * 16 + quad * 4 + r][1] = Slp[r];
      st[wc][wm * 16 + quad * 4 + r][2] = Sup[r];
    }
  }
  __syncthreads();
  float rSv4[4], Sl4[4], Su4[4];
#pragma unroll
  for (int r = 0; r < 4; r++) {
    const int row = wm * 16 + quad * 4 + r;
    rSv4[r] = 1.f / (st[0][row][0] + st[1][row][0]);
    Sl4[r]  = st[0][row][1] + st[1][row][1];
    Su4[r]  = st[0][row][2] + st[1][row][2];
  }

  // ---- pass 2: p and P@V (d-split PV) ----
  f32x4 oa[3][2];
#pragma unroll
  for (int bo = 0; bo < 3; bo++)
#pragma unroll
    for (int ds = 0; ds < 2; ds++) oa[bo][ds] = (f32x4){0.f, 0.f, 0.f, 0.f};

  for (int ct = 0; ct < 16; ct++) {
    const int c0 = ct * 32;
    __syncthreads();
#pragma unroll
    for (int pI = 0; pI < 3; pI++) {
      *(uint4*)(Ks + pI * 2304 + krow * KS + kseg * 8) =
          *(const uint4*)(kplane[pI] + (size_t)(b * SEQ + c0 + krow) * 3072 + 1024 + h * 64 + kseg * 8);
      *(uint4*)(Vs + pI * 2560 + vrow * VS + vseg * 8) =
          *(const uint4*)(vplane[pI] + (size_t)(bh * 64 + vrow) * 512 + c0 + vseg * 8);
    }
    __syncthreads();

    f32x4 av, al, au;
    qk_tile(Ks, Ks + 2304, Ks + 4608, cl, quad,
            qvf, qlpf, qlnf, qupf, qunf, &av, &al, &au);
#pragma unroll
    for (int r = 0; r < 4; r++) {
      const float ev = __expf(av[r]);
      const float el = __expf(al[r]);
      const float eu = __expf(au[r]);
      float pl = el * __builtin_amdgcn_rcpf(Su4[r] - eu + el);
      float pu = eu * __builtin_amdgcn_rcpf(Sl4[r] - el + eu);
      pl = fminf(fmaxf(pl, 0.f), 1.f);
      pu = fminf(fmaxf(pu, 0.f), 1.f);
      const int prow = (wm * 16 + quad * 4 + r) * VS + cl;
      Ps[prow]        = f2b_fast(ev);   // unnormalized; 1/Sv folded in epilogue
      Ps[1280 + prow] = f2b_fast(pl);
      Ps[2560 + prow] = f2b_fast(pu);
    }
    __syncthreads();

#pragma unroll
    for (int ds = 0; ds < 2; ds++) {
      const int dsub = wc * 2 + ds;
      const int voff = (dsub * 16 + r16) * VS + quad * 8;
      bf16x8 vv = *(const bf16x8*)(Vs + voff);
      bf16x8 vl = *(const bf16x8*)(Vs + 2560 + voff);
      bf16x8 vu = *(const bf16x8*)(Vs + 5120 + voff);
      bf16x8 vlp, vln, vup, vun;
      clamp_pn8(vl, &vlp, &vln);
      clamp_pn8(vu, &vup, &vun);
      const int arow = (wm * 16 + r16) * VS + quad * 8;
      bf16x8 pav = *(const bf16x8*)(Ps + arow);
      bf16x8 pal = *(const bf16x8*)(Ps + 1280 + arow);
      bf16x8 pau = *(const bf16x8*)(Ps + 2560 + arow);
      oa[0][ds] = MFMA16(pav, vv, oa[0][ds]);
      oa[1][ds] = MFMA16(pal, vlp, oa[1][ds]);
      oa[1][ds] = MFMA16(pau, vln, oa[1][ds]);
      oa[2][ds] = MFMA16(pau, vup, oa[2][ds]);
      oa[2][ds] = MFMA16(pal, vun, oa[2][ds]);
    }
  }

  // ---- epilogue: bf16 stores into Ov / Oc / Or planes [2048][1024] ----
#pragma unroll
  for (int ds = 0; ds < 2; ds++) {
    const int dsub = wc * 2 + ds;
#pragma unroll
    for (int r = 0; r < 4; r++) {
      const size_t row = (size_t)(mq + wm * 16 + quad * 4 + r);
      const int col = h * 64 + dsub * 16 + r16;
      const float ovv = oa[0][ds][r] * rSv4[r];
      const float olv = oa[1][ds][r];
      const float ouv = oa[2][ds][r];
      Ov[row * 1024 + col] = f2b(ovv);
      Oc[row * 1024 + col] = f2b(0.5f * (olv + ouv));
      Or[row * 1024 + col] = f2b(0.5f * (ouv - olv));
    }
  }
}

// ---------------------------------------------------------------------------
extern "C" void kernel_launch(void* const* d_in, const int* in_sizes, int n_in,
                              void* d_out, int out_size, void* d_ws, size_t ws_size,
                              hipStream_t stream)
{
  const float* x_val = (const float*)d_in[0];
  const float* x_lb  = (const float*)d_in[1];
  const float* x_ub  = (const float*)d_in[2];
  const float* Wi    = (const float*)d_in[3];
  const float* bi    = (const float*)d_in[4];
  const float* Wo    = (const float*)d_in[5];
  const float* bo    = (const float*)d_in[6];
  float* out = (float*)d_out;

  // ws layout (~79 MB). Xv/Xc/Xr reused as attn outputs Ov/Oc/Or (bf16).
  char* p = (char*)d_ws;
  unsigned short* Xv  = (unsigned short*)p; p += (size_t)2048 * 1024 * 2;  // then Ov
  unsigned short* Xc  = (unsigned short*)p; p += (size_t)2048 * 1024 * 2;  // then Oc
  unsigned short* Xr  = (unsigned short*)p; p += (size_t)2048 * 1024 * 2;  // then Or
  unsigned short* Wit = (unsigned short*)p; p += (size_t)3072 * 1024 * 2;
  unsigned short* Wia = (unsigned short*)p; p += (size_t)3072 * 1024 * 2;
  unsigned short* Wot = (unsigned short*)p; p += (size_t)1024 * 1024 * 2;
  unsigned short* Woa = (unsigned short*)p; p += (size_t)1024 * 1024 * 2;
  unsigned short* qv  = (unsigned short*)p; p += (size_t)2048 * 3072 * 2;
  unsigned short* ql  = (unsigned short*)p; p += (size_t)2048 * 3072 * 2;
  unsigned short* qu  = (unsigned short*)p; p += (size_t)2048 * 3072 * 2;
  unsigned short* Vtv = (unsigned short*)p; p += (size_t)64 * 64 * 512 * 2;
  unsigned short* Vtl = (unsigned short*)p; p += (size_t)64 * 64 * 512 * 2;
  unsigned short* Vtu = (unsigned short*)p; p += (size_t)64 * 64 * 512 * 2;

  // 1) convert inputs + weights to bf16
  convert_stack<<<2048, 256, 0, stream>>>(x_val, x_lb, x_ub, Xv, Xc, Xr, 524288);
  wt_convert<<<dim3(96, 32), dim3(32, 8), 0, stream>>>(Wi, Wit, Wia, 1024, 3072);
  wt_convert<<<dim3(32, 32), dim3(32, 8), 0, stream>>>(Wo, Wot, Woa, 1024, 1024);

  // 2) in_proj: value GEMM + fused center/radius GEMM (emit qkv + Vt planes)
  gemm_v_bf16<<<dim3(24, 32), 256, 0, stream>>>(Xv, Wit, 1024, bi,
                                                nullptr, qv, Vtv, 3072);
  gemm_cr_bf16<<<dim3(24, 32), 256, 0, stream>>>(Xc, Xr, Wit, Wia, 1024, bi,
                                                 nullptr, nullptr, ql, qu, Vtl, Vtu, 3072);

  // 3) MFMA IBP attention -> bf16 planes Ov/Oc/Or (alias Xv/Xc/Xr)
  ibp_attn_mfma<<<dim3(SEQ / 32, NHEAD, NBAT), 256, 0, stream>>>(
      qv, ql, qu, Vtv, Vtl, Vtu, Xv, Xc, Xr);

  // 4) out_proj: value GEMM + fused center/radius GEMM -> [3,B,S,E] fp32
  gemm_v_bf16<<<dim3(8, 32), 256, 0, stream>>>(Xv, Wot, 1024, bo,
                                               out, nullptr, nullptr, 1024);
  gemm_cr_bf16<<<dim3(8, 32), 256, 0, stream>>>(Xc, Xr, Wot, Woa, 1024, bo,
                                                out + (size_t)2048 * 1024,
                                                out + (size_t)4096 * 1024,
                                                nullptr, nullptr, nullptr, nullptr, 1024);
}

// Round 8
// 313.921 us; speedup vs baseline: 5.6072x; 1.0193x over previous
//
#include <hip/hip_runtime.h>
#include <math.h>

#define SEQ    512
#define EMB    1024
#define NHEAD  16
#define DHEAD  64
#define NBAT   4
#define QSCALE 0.125f   // 1/sqrt(64)
#define KS     72       // attn K-tile row stride (ushorts)
#define VS     40       // attn V/P tile row stride (ushorts)

typedef __attribute__((ext_vector_type(8))) short bf16x8;
typedef __attribute__((ext_vector_type(4))) float f32x4;

#define MFMA16(a, b, c) __builtin_amdgcn_mfma_f32_16x16x32_bf16(a, b, c, 0, 0, 0)

__device__ __forceinline__ unsigned short f2b(float x) {
  union { float f; unsigned int u; } a; a.f = x;
  unsigned int u = a.u;
  unsigned int r = (u + 0x7fffu + ((u >> 16) & 1u)) >> 16;   // RNE
  return (unsigned short)r;
}
__device__ __forceinline__ unsigned short f2b_fast(float x) {
  union { float f; unsigned int u; } a; a.f = x;
  return (unsigned short)((a.u + 0x8000u) >> 16);            // round-half-up
}
__device__ __forceinline__ float b2f(unsigned short x) {
  union { unsigned int u; float f; } a; a.u = ((unsigned int)x) << 16; return a.f;
}

// async global->LDS 16B: lds dst is wave-uniform base (+ lane*16 by HW)
__device__ __forceinline__ void async16(const unsigned short* g, unsigned short* lds) {
  __builtin_amdgcn_global_load_lds(
      (const __attribute__((address_space(1))) unsigned int*)g,
      (__attribute__((address_space(3))) unsigned int*)lds, 16, 0, 0);
}

// packed sign-based split of bf16x8 into positive/negative parts (exact)
__device__ __forceinline__ void clamp_pn8(bf16x8 x, bf16x8* p, bf16x8* n) {
  const unsigned int* xu = (const unsigned int*)&x;
  unsigned int* pp = (unsigned int*)p;
  unsigned int* nn = (unsigned int*)n;
#pragma unroll
  for (int e = 0; e < 4; e++) {
    const unsigned int s = xu[e] & 0x80008000u;
    const unsigned int mask = s | (s - (s >> 15));   // 0xFFFF in negative halves
    nn[e] = xu[e] & mask;
    pp[e] = xu[e] & ~mask;
  }
}

__device__ __forceinline__ float wave16_sum(float x) {
#pragma unroll
  for (int m = 1; m <= 8; m <<= 1) x += __shfl_xor(x, m);
  return x;
}

// ---------------------------------------------------------------------------
// convert v,l,u fp32 -> bf16 planes Xv, Xc, Xr (all [M][1024])
// ---------------------------------------------------------------------------
__global__ __launch_bounds__(256)
void convert_stack(const float* __restrict__ v, const float* __restrict__ l,
                   const float* __restrict__ u,
                   unsigned short* __restrict__ outV,
                   unsigned short* __restrict__ outC,
                   unsigned short* __restrict__ outR, int total4)
{
  int i = blockIdx.x * 256 + threadIdx.x;
  if (i >= total4) return;
  float4 v4 = ((const float4*)v)[i];
  float4 l4 = ((const float4*)l)[i];
  float4 u4 = ((const float4*)u)[i];
  float lv[4] = {l4.x, l4.y, l4.z, l4.w};
  float uv[4] = {u4.x, u4.y, u4.z, u4.w};
  float vv[4] = {v4.x, v4.y, v4.z, v4.w};
  ushort4 ov, oc, orr;
  unsigned short* pv = (unsigned short*)&ov;
  unsigned short* pc = (unsigned short*)&oc;
  unsigned short* pr = (unsigned short*)&orr;
#pragma unroll
  for (int e = 0; e < 4; e++) {
    pv[e] = f2b(vv[e]);
    pc[e] = f2b(0.5f * (lv[e] + uv[e]));
    pr[e] = f2b(0.5f * (uv[e] - lv[e]));
  }
  ((ushort4*)outV)[i] = ov;
  ((ushort4*)outC)[i] = oc;
  ((ushort4*)outR)[i] = orr;
}

// ---------------------------------------------------------------------------
// W [K][N] fp32 -> Wt [N][K] bf16 and Wabs_t [N][K] bf16 (tiled transpose)
// ---------------------------------------------------------------------------
__global__ __launch_bounds__(256)
void wt_convert(const float* __restrict__ W,
                unsigned short* __restrict__ Wt,
                unsigned short* __restrict__ Wa, int K, int N)
{
  __shared__ float tile[32][33];
  const int n0 = blockIdx.x * 32, k0 = blockIdx.y * 32;
  const int tx = threadIdx.x, ty = threadIdx.y;   // 32 x 8
#pragma unroll
  for (int r = 0; r < 32; r += 8)
    tile[ty + r][tx] = W[(size_t)(k0 + ty + r) * N + n0 + tx];
  __syncthreads();
#pragma unroll
  for (int r = 0; r < 32; r += 8) {
    const float w = tile[tx][ty + r];
    const size_t o = (size_t)(n0 + ty + r) * K + k0 + tx;
    Wt[o] = f2b(w);
    Wa[o] = f2b(fabsf(w));
  }
}

// ---------------------------------------------------------------------------
// Fused IBP projection GEMM: 3 accumulator sets sharing staged B tiles.
//   v = Av@Bt + b ; l = Ac@Bt - Ar@Ba + b ; u = Ac@Bt + Ar@Ba + b
// BM=64, BN templated (128 in_proj / 64 out_proj), BK=32, 256 threads,
// double-buffered async16 staging, one barrier per k-iter.
// Optional transposed V side-output for n>=2048 (in_proj only).
// ---------------------------------------------------------------------------
template<int BN>
__global__ __launch_bounds__(256, 2)
void gemm_ibp3(const unsigned short* __restrict__ Av,
               const unsigned short* __restrict__ Ac,
               const unsigned short* __restrict__ Ar,
               const unsigned short* __restrict__ Bt,
               const unsigned short* __restrict__ Ba,
               int K, const float* __restrict__ bias,
               float* __restrict__ oV, float* __restrict__ oL, float* __restrict__ oU,
               unsigned short* __restrict__ hV, unsigned short* __restrict__ hL,
               unsigned short* __restrict__ hU,
               unsigned short* __restrict__ vtV, unsigned short* __restrict__ vtL,
               unsigned short* __restrict__ vtU, int N)
{
  constexpr int NF = BN / 32;   // n-frags per wave
  __shared__ __attribute__((aligned(16))) unsigned short Avs[2][64 * 32];
  __shared__ __attribute__((aligned(16))) unsigned short Acs[2][64 * 32];
  __shared__ __attribute__((aligned(16))) unsigned short Ars[2][64 * 32];
  __shared__ __attribute__((aligned(16))) unsigned short Bts[2][BN * 32];
  __shared__ __attribute__((aligned(16))) unsigned short Bas[2][BN * 32];

  const int t = threadIdx.x, lane = t & 63, w = t >> 6;
  const int m0 = blockIdx.y * 64, n0 = blockIdx.x * BN;
  const int wm = w & 1, wn = w >> 1;
  const int quad = lane >> 4, r16 = lane & 15;
  const int srow = lane >> 2, sseg = lane & 3;

  f32x4 av[2][NF], ac[2][NF], ar[2][NF];
#pragma unroll
  for (int i = 0; i < 2; i++)
#pragma unroll
    for (int j = 0; j < NF; j++) {
      av[i][j] = (f32x4){0.f, 0.f, 0.f, 0.f};
      ac[i][j] = (f32x4){0.f, 0.f, 0.f, 0.f};
      ar[i][j] = (f32x4){0.f, 0.f, 0.f, 0.f};
    }

  const int iters = K >> 5;
  auto stage = [&](int it, int buf) {
    const int k0 = it * 32;
    const size_t ga = (size_t)(m0 + 16 * w + srow) * K + k0 + sseg * 8;
    async16(Av + ga, &Avs[buf][16 * w * 32]);
    async16(Ac + ga, &Acs[buf][16 * w * 32]);
    async16(Ar + ga, &Ars[buf][16 * w * 32]);
#pragma unroll
    for (int r = 0; r < BN / 64; r++) {
      const int brow = (BN / 4) * w + 16 * r;
      const size_t gb = (size_t)(n0 + brow + srow) * K + k0 + sseg * 8;
      async16(Bt + gb, &Bts[buf][brow * 32]);
      async16(Ba + gb, &Bas[buf][brow * 32]);
    }
  };

  stage(0, 0);
  for (int it = 0; it < iters; ++it) {
    const int cur = it & 1;
    __syncthreads();                       // drains cur's loads (all waves)
    if (it + 1 < iters) stage(it + 1, cur ^ 1);
    bf16x8 fv[2], fc[2], fr[2], gt[NF], gb[NF];
#pragma unroll
    for (int i = 0; i < 2; i++) {
      const int off = (wm * 32 + i * 16 + r16) * 32 + quad * 8;
      fv[i] = *(const bf16x8*)(&Avs[cur][off]);
      fc[i] = *(const bf16x8*)(&Acs[cur][off]);
      fr[i] = *(const bf16x8*)(&Ars[cur][off]);
    }
#pragma unroll
    for (int j = 0; j < NF; j++) {
      const int off = (wn * (BN / 2) + j * 16 + r16) * 32 + quad * 8;
      gt[j] = *(const bf16x8*)(&Bts[cur][off]);
      gb[j] = *(const bf16x8*)(&Bas[cur][off]);
    }
#pragma unroll
    for (int i = 0; i < 2; i++)
#pragma unroll
      for (int j = 0; j < NF; j++) {
        av[i][j] = MFMA16(fv[i], gt[j], av[i][j]);
        ac[i][j] = MFMA16(fc[i], gt[j], ac[i][j]);
        ar[i][j] = MFMA16(fr[i], gb[j], ar[i][j]);
      }
  }

  // epilogue: C/D layout col=lane&15, row=quad*4+reg
#pragma unroll
  for (int i = 0; i < 2; i++) {
    const int mbase = m0 + wm * 32 + i * 16 + quad * 4;
#pragma unroll
    for (int j = 0; j < NF; j++) {
      const int n = n0 + wn * (BN / 2) + j * 16 + r16;
      const float bv = bias[n];
      float vv[4], lv[4], uv[4];
#pragma unroll
      for (int rI = 0; rI < 4; rI++) {
        const float c = ac[i][j][rI], r = ar[i][j][rI];
        vv[rI] = av[i][j][rI] + bv;
        lv[rI] = c - r + bv;
        uv[rI] = c + r + bv;
      }
      if (hV) {
#pragma unroll
        for (int rI = 0; rI < 4; rI++) {
          hV[(size_t)(mbase + rI) * N + n] = f2b(vv[rI]);
          hL[(size_t)(mbase + rI) * N + n] = f2b(lv[rI]);
          hU[(size_t)(mbase + rI) * N + n] = f2b(uv[rI]);
        }
      } else {
#pragma unroll
        for (int rI = 0; rI < 4; rI++) {
          oV[(size_t)(mbase + rI) * N + n] = vv[rI];
          oL[(size_t)(mbase + rI) * N + n] = lv[rI];
          oU[(size_t)(mbase + rI) * N + n] = uv[rI];
        }
      }
      if (vtV && n >= 2048) {
        const int hh = (n - 2048) >> 6, dd = (n - 2048) & 63;
        const int bb = mbase >> 9, ss = mbase & 511;
        ushort4 v4, l4, u4;
        unsigned short* vp = (unsigned short*)&v4;
        unsigned short* lp = (unsigned short*)&l4;
        unsigned short* up = (unsigned short*)&u4;
#pragma unroll
        for (int rI = 0; rI < 4; rI++) {
          vp[rI] = f2b(vv[rI]); lp[rI] = f2b(lv[rI]); up[rI] = f2b(uv[rI]);
        }
        const size_t vo = (size_t)((bb * 16 + hh) * 64 + dd) * 512 + ss;
        *(ushort4*)(vtV + vo) = v4;
        *(ushort4*)(vtL + vo) = l4;
        *(ushort4*)(vtU + vo) = u4;
      }
    }
  }
}

// ---------------------------------------------------------------------------
// one 16x16 S sub-tile: 18 MFMA over K=64 (value 2, lb 8, ub 8)
// ---------------------------------------------------------------------------
__device__ __forceinline__ void qk_tile(const unsigned short* K0,
                                        const unsigned short* K1,
                                        const unsigned short* K2,
                                        int cl, int quad,
                                        const bf16x8 qvf[2], const bf16x8 qlpf[2],
                                        const bf16x8 qlnf[2], const bf16x8 qupf[2],
                                        const bf16x8 qunf[2],
                                        f32x4* avp, f32x4* alp, f32x4* aup)
{
  f32x4 v = {0.f, 0.f, 0.f, 0.f}, l = v, u = v;
#pragma unroll
  for (int kh = 0; kh < 2; kh++) {
    const int off = cl * KS + kh * 32 + quad * 8;
    bf16x8 kv = *(const bf16x8*)(K0 + off);
    bf16x8 kl = *(const bf16x8*)(K1 + off);
    bf16x8 ku = *(const bf16x8*)(K2 + off);
    bf16x8 klp, kln, kup, kun;
    clamp_pn8(kl, &klp, &kln);
    clamp_pn8(ku, &kup, &kun);
    v = MFMA16(qvf[kh], kv, v);
    l = MFMA16(qlpf[kh], klp, l);
    l = MFMA16(qupf[kh], kln, l);
    l = MFMA16(qlnf[kh], kup, l);
    l = MFMA16(qunf[kh], kun, l);
    u = MFMA16(qupf[kh], kup, u);
    u = MFMA16(qlpf[kh], kun, u);
    u = MFMA16(qunf[kh], klp, u);
    u = MFMA16(qlnf[kh], kln, u);
  }
  *avp = v; *alp = l; *aup = u;
}

// ---------------------------------------------------------------------------
// MFMA IBP attention v3 (R6 structure); Ps written as lane-paired packed
// dwords (2-way banks, was 4-way ushort scatter). Outputs split planes
// Ov / Oc / Or (bf16, [2048][1024]) feeding gemm_ibp3 directly.
// ---------------------------------------------------------------------------
__global__ __launch_bounds__(256, 4)
void ibp_attn_mfma(const unsigned short* __restrict__ qkv_v,
                   const unsigned short* __restrict__ qkv_l,
                   const unsigned short* __restrict__ qkv_u,
                   const unsigned short* __restrict__ vt_v,
                   const unsigned short* __restrict__ vt_l,
                   const unsigned short* __restrict__ vt_u,
                   unsigned short* __restrict__ Ov,
                   unsigned short* __restrict__ Oc,
                   unsigned short* __restrict__ Or)
{
  __shared__ __attribute__((aligned(16))) unsigned short pool[6912 + 7680 + 3840];
  __shared__ float st[2][32][3];
  unsigned short* Ks = pool;                 // 3 planes, stride 2304
  unsigned short* Vs = pool + 6912;          // 3 planes, stride 2560
  unsigned short* Ps = pool + 6912 + 7680;   // 3 planes, stride 1280

  const int qblk = blockIdx.x, h = blockIdx.y, b = blockIdx.z;
  const int t = threadIdx.x, lane = t & 63, w = t >> 6;
  const int wm = w >> 1, wc = w & 1;
  const int quad = lane >> 4, r16 = lane & 15;
  const int mq = b * SEQ + qblk * 32;
  const int bh = b * NHEAD + h;

  bf16x8 qvf[2], qlpf[2], qlnf[2], qupf[2], qunf[2];
  {
    const size_t qrow = (size_t)(mq + wm * 16 + r16) * 3072 + h * 64;
#pragma unroll
    for (int kh = 0; kh < 2; kh++) {
      bf16x8 v8 = *(const bf16x8*)(qkv_v + qrow + kh * 32 + quad * 8);
      bf16x8 l8 = *(const bf16x8*)(qkv_l + qrow + kh * 32 + quad * 8);
      bf16x8 u8 = *(const bf16x8*)(qkv_u + qrow + kh * 32 + quad * 8);
      const unsigned short* vs = (const unsigned short*)&v8;
      const unsigned short* ls = (const unsigned short*)&l8;
      const unsigned short* us = (const unsigned short*)&u8;
      unsigned short* ov = (unsigned short*)&qvf[kh];
      unsigned short* lp = (unsigned short*)&qlpf[kh];
      unsigned short* ln = (unsigned short*)&qlnf[kh];
      unsigned short* up = (unsigned short*)&qupf[kh];
      unsigned short* un = (unsigned short*)&qunf[kh];
#pragma unroll
      for (int e = 0; e < 8; e++) {
        ov[e] = f2b(b2f(vs[e]) * QSCALE);
        const float lf = b2f(ls[e]) * QSCALE;
        const float uf = b2f(us[e]) * QSCALE;
        lp[e] = f2b(fmaxf(lf, 0.f)); ln[e] = f2b(fminf(lf, 0.f));
        up[e] = f2b(fmaxf(uf, 0.f)); un[e] = f2b(fminf(uf, 0.f));
      }
    }
  }

  const int cl = wc * 16 + r16;
  const int krow = t >> 3, kseg = t & 7;
  const int vrow = t >> 2, vseg = t & 3;
  const unsigned short* kplane[3] = {qkv_v, qkv_l, qkv_u};
  const unsigned short* vplane[3] = {vt_v, vt_l, vt_u};

  // ---- pass 1: raw exp row-sums (ping-pong K) ----
  float Svp[4] = {0.f, 0.f, 0.f, 0.f};
  float Slp[4] = {0.f, 0.f, 0.f, 0.f};
  float Sup[4] = {0.f, 0.f, 0.f, 0.f};

#pragma unroll
  for (int pI = 0; pI < 3; pI++)
    *(uint4*)(Ks + pI * 2304 + krow * KS + kseg * 8) =
        *(const uint4*)(kplane[pI] + (size_t)(b * SEQ + krow) * 3072 + 1024 + h * 64 + kseg * 8);
  __syncthreads();

  for (int ct = 0; ct < 16; ct++) {
    const unsigned short* cur = (ct & 1) ? Vs : Ks;
    if (ct < 15) {
      unsigned short* nxt = (ct & 1) ? Ks : Vs;
      const int c0n = (ct + 1) * 32;
#pragma unroll
      for (int pI = 0; pI < 3; pI++)
        *(uint4*)(nxt + pI * 2304 + krow * KS + kseg * 8) =
            *(const uint4*)(kplane[pI] + (size_t)(b * SEQ + c0n + krow) * 3072 + 1024 + h * 64 + kseg * 8);
    }
    f32x4 av, al, au;
    qk_tile(cur, cur + 2304, cur + 4608, cl, quad,
            qvf, qlpf, qlnf, qupf, qunf, &av, &al, &au);
#pragma unroll
    for (int r = 0; r < 4; r++) {
      Svp[r] += __expf(av[r]);
      Slp[r] += __expf(al[r]);
      Sup[r] += __expf(au[r]);
    }
    __syncthreads();
  }

#pragma unroll
  for (int r = 0; r < 4; r++) {
    Svp[r] = wave16_sum(Svp[r]);
    Slp[r] = wave16_sum(Slp[r]);
    Sup[r] = wave16_sum(Sup[r]);
  }
  if (r16 == 0) {
#pragma unroll
    for (int r = 0; r < 4; r++) {
      st[wc][wm * 16 + quad * 4 + r][0] = Svp[r];
      st[wc][wm * 16 + quad * 4 + r][1] = Slp[r];
      st[wc][wm * 16 + quad * 4 + r][2] = Sup[r];
    }
  }
  __syncthreads();
  float rSv4[4], Sl4[4], Su4[4];
#pragma unroll
  for (int r = 0; r < 4; r++) {
    const int row = wm * 16 + quad * 4 + r;
    rSv4[r] = 1.f / (st[0][row][0] + st[1][row][0]);
    Sl4[r]  = st[0][row][1] + st[1][row][1];
    Su4[r]  = st[0][row][2] + st[1][row][2];
  }

  // ---- pass 2: p and P@V (d-split PV) ----
  f32x4 oa[3][2];
#pragma unroll
  for (int bo = 0; bo < 3; bo++)
#pragma unroll
    for (int ds = 0; ds < 2; ds++) oa[bo][ds] = (f32x4){0.f, 0.f, 0.f, 0.f};

  for (int ct = 0; ct < 16; ct++) {
    const int c0 = ct * 32;
    __syncthreads();
#pragma unroll
    for (int pI = 0; pI < 3; pI++) {
      *(uint4*)(Ks + pI * 2304 + krow * KS + kseg * 8) =
          *(const uint4*)(kplane[pI] + (size_t)(b * SEQ + c0 + krow) * 3072 + 1024 + h * 64 + kseg * 8);
      *(uint4*)(Vs + pI * 2560 + vrow * VS + vseg * 8) =
          *(const uint4*)(vplane[pI] + (size_t)(bh * 64 + vrow) * 512 + c0 + vseg * 8);
    }
    __syncthreads();

    f32x4 av, al, au;
    qk_tile(Ks, Ks + 2304, Ks + 4608, cl, quad,
            qvf, qlpf, qlnf, qupf, qunf, &av, &al, &au);
#pragma unroll
    for (int r = 0; r < 4; r++) {
      const float ev = __expf(av[r]);
      const float el = __expf(al[r]);
      const float eu = __expf(au[r]);
      float pl = el * __builtin_amdgcn_rcpf(Su4[r] - eu + el);
      float pu = eu * __builtin_amdgcn_rcpf(Sl4[r] - el + eu);
      pl = fminf(fmaxf(pl, 0.f), 1.f);
      pu = fminf(fmaxf(pu, 0.f), 1.f);
      // lane-pair pack: even r16 writes dword covering columns (cl, cl+1)
      const float pev = __shfl_xor(ev, 1);
      const float ppl = __shfl_xor(pl, 1);
      const float ppu = __shfl_xor(pu, 1);
      if (!(r16 & 1)) {
        const unsigned int wv = (unsigned int)f2b_fast(ev) | ((unsigned int)f2b_fast(pev) << 16);
        const unsigned int wl = (unsigned int)f2b_fast(pl) | ((unsigned int)f2b_fast(ppl) << 16);
        const unsigned int wu = (unsigned int)f2b_fast(pu) | ((unsigned int)f2b_fast(ppu) << 16);
        const int prow = (wm * 16 + quad * 4 + r) * VS + cl;   // cl even -> 4B aligned
        *(unsigned int*)(Ps + prow)        = wv;
        *(unsigned int*)(Ps + 1280 + prow) = wl;
        *(unsigned int*)(Ps + 2560 + prow) = wu;
      }
    }
    __syncthreads();

#pragma unroll
    for (int ds = 0; ds < 2; ds++) {
      const int dsub = wc * 2 + ds;
      const int voff = (dsub * 16 + r16) * VS + quad * 8;
      bf16x8 vv = *(const bf16x8*)(Vs + voff);
      bf16x8 vl = *(const bf16x8*)(Vs + 2560 + voff);
      bf16x8 vu = *(const bf16x8*)(Vs + 5120 + voff);
      bf16x8 vlp, vln, vup, vun;
      clamp_pn8(vl, &vlp, &vln);
      clamp_pn8(vu, &vup, &vun);
      const int arow = (wm * 16 + r16) * VS + quad * 8;
      bf16x8 pav = *(const bf16x8*)(Ps + arow);
      bf16x8 pal = *(const bf16x8*)(Ps + 1280 + arow);
      bf16x8 pau = *(const bf16x8*)(Ps + 2560 + arow);
      oa[0][ds] = MFMA16(pav, vv, oa[0][ds]);
      oa[1][ds] = MFMA16(pal, vlp, oa[1][ds]);
      oa[1][ds] = MFMA16(pau, vln, oa[1][ds]);
      oa[2][ds] = MFMA16(pau, vup, oa[2][ds]);
      oa[2][ds] = MFMA16(pal, vun, oa[2][ds]);
    }
  }

  // ---- epilogue: bf16 stores into Ov / Oc / Or planes [2048][1024] ----
#pragma unroll
  for (int ds = 0; ds < 2; ds++) {
    const int dsub = wc * 2 + ds;
#pragma unroll
    for (int r = 0; r < 4; r++) {
      const size_t row = (size_t)(mq + wm * 16 + quad * 4 + r);
      const int col = h * 64 + dsub * 16 + r16;
      const float ovv = oa[0][ds][r] * rSv4[r];
      const float olv = oa[1][ds][r];
      const float ouv = oa[2][ds][r];
      Ov[row * 1024 + col] = f2b(ovv);
      Oc[row * 1024 + col] = f2b(0.5f * (olv + ouv));
      Or[row * 1024 + col] = f2b(0.5f * (ouv - olv));
    }
  }
}

// ---------------------------------------------------------------------------
extern "C" void kernel_launch(void* const* d_in, const int* in_sizes, int n_in,
                              void* d_out, int out_size, void* d_ws, size_t ws_size,
                              hipStream_t stream)
{
  const float* x_val = (const float*)d_in[0];
  const float* x_lb  = (const float*)d_in[1];
  const float* x_ub  = (const float*)d_in[2];
  const float* Wi    = (const float*)d_in[3];
  const float* bi    = (const float*)d_in[4];
  const float* Wo    = (const float*)d_in[5];
  const float* bo    = (const float*)d_in[6];
  float* out = (float*)d_out;

  // ws layout (~79 MB). Xv/Xc/Xr reused as attn outputs Ov/Oc/Or (bf16).
  char* p = (char*)d_ws;
  unsigned short* Xv  = (unsigned short*)p; p += (size_t)2048 * 1024 * 2;  // then Ov
  unsigned short* Xc  = (unsigned short*)p; p += (size_t)2048 * 1024 * 2;  // then Oc
  unsigned short* Xr  = (unsigned short*)p; p += (size_t)2048 * 1024 * 2;  // then Or
  unsigned short* Wit = (unsigned short*)p; p += (size_t)3072 * 1024 * 2;
  unsigned short* Wia = (unsigned short*)p; p += (size_t)3072 * 1024 * 2;
  unsigned short* Wot = (unsigned short*)p; p += (size_t)1024 * 1024 * 2;
  unsigned short* Woa = (unsigned short*)p; p += (size_t)1024 * 1024 * 2;
  unsigned short* qv  = (unsigned short*)p; p += (size_t)2048 * 3072 * 2;
  unsigned short* ql  = (unsigned short*)p; p += (size_t)2048 * 3072 * 2;
  unsigned short* qu  = (unsigned short*)p; p += (size_t)2048 * 3072 * 2;
  unsigned short* Vtv = (unsigned short*)p; p += (size_t)64 * 64 * 512 * 2;
  unsigned short* Vtl = (unsigned short*)p; p += (size_t)64 * 64 * 512 * 2;
  unsigned short* Vtu = (unsigned short*)p; p += (size_t)64 * 64 * 512 * 2;

  // 1) convert inputs + weights to bf16
  convert_stack<<<2048, 256, 0, stream>>>(x_val, x_lb, x_ub, Xv, Xc, Xr, 524288);
  wt_convert<<<dim3(96, 32), dim3(32, 8), 0, stream>>>(Wi, Wit, Wia, 1024, 3072);
  wt_convert<<<dim3(32, 32), dim3(32, 8), 0, stream>>>(Wo, Wot, Woa, 1024, 1024);

  // 2) in_proj: ONE fused triple GEMM (emits qv/ql/qu + transposed Vt planes)
  gemm_ibp3<128><<<dim3(3072 / 128, 32), 256, 0, stream>>>(
      Xv, Xc, Xr, Wit, Wia, 1024, bi,
      nullptr, nullptr, nullptr, qv, ql, qu, Vtv, Vtl, Vtu, 3072);

  // 3) MFMA IBP attention -> bf16 planes Ov/Oc/Or (alias Xv/Xc/Xr)
  ibp_attn_mfma<<<dim3(SEQ / 32, NHEAD, NBAT), 256, 0, stream>>>(
      qv, ql, qu, Vtv, Vtl, Vtu, Xv, Xc, Xr);

  // 4) out_proj: ONE fused triple GEMM -> [3,B,S,E] fp32
  gemm_ibp3<64><<<dim3(1024 / 64, 32), 256, 0, stream>>>(
      Xv, Xc, Xr, Wot, Woa, 1024, bo,
      out, out + (size_t)2048 * 1024, out + (size_t)4096 * 1024,
      nullptr, nullptr, nullptr, nullptr, nullptr, nullptr, 1024);
}